// Round 6
// baseline (753.098 us; speedup 1.0000x reference)
//
#include <hip/hip_runtime.h>
#include <hip/hip_bf16.h>

// EquivariantBlock — Round 6.
// R4/R5 evidence: k_edge1 pinned at 82M fp32 atomics / ~275 G dword-atomics/s
// (271 G/s R4, 278 G/s R5 with totally different occupancy) -> L2 atomic-op wall.
// Fix: CSR-order the edges (hist/scan/scatter each call), write msg bf16 to the
// d_s LDS overlay, segmented-reduce per node segment -> ~7.7M atomics (10x cut).
// hh fp32 lives in d_out (node_lin writes, node2 reads then overwrites).

#define D 128
#define RS 136          // LDS row stride in bf16 units (128 + 8 pad)

typedef unsigned short ushort;
typedef __attribute__((ext_vector_type(8))) short short8;
typedef __attribute__((ext_vector_type(4))) float f32x4;

__device__ __forceinline__ float siluf(float x) { return x / (1.0f + __expf(-x)); }
__device__ __forceinline__ float sigmf(float x) { return 1.0f / (1.0f + __expf(-x)); }
__device__ __forceinline__ ushort f2bs(float f) {
    __hip_bfloat16 b = __float2bfloat16(f);
    ushort u; __builtin_memcpy(&u, &b, 2); return u;
}
__device__ __forceinline__ unsigned pkbf(float lo, float hi) {
    __hip_bfloat162 h2 = __float22bfloat162_rn(make_float2(lo, hi));
    unsigned u; __builtin_memcpy(&u, &h2, 4); return u;
}
__device__ __forceinline__ float bs2f(ushort u) {
    return __uint_as_float(((unsigned)u) << 16);
}
#define MFMA16(a, b, c) __builtin_amdgcn_mfma_f32_16x16x32_bf16((a), (b), (c), 0, 0, 0)

// packed-weight block offsets (units of 4096 ushorts)
#define PWLIN 0
#define PWA1  5
#define PWE1  14
#define PWE2  19
#define PWN1  23
#define PWN2  28
#define PWC1  32
#define PWC2  41
#define NPACK 45

// ---------------- zero scratch ----------------
__global__ void k_zero(float* __restrict__ p, long n) {
    long i = (long)blockIdx.x * blockDim.x + threadIdx.x;
    long stride = (long)gridDim.x * blockDim.x;
    for (; i < n; i += stride) p[i] = 0.0f;
}

// ---------------- CSR build ----------------
__global__ void k_hist(const int* __restrict__ eidx, int* __restrict__ cnt, int E) {
    int i = blockIdx.x * blockDim.x + threadIdx.x;
    const int stride = gridDim.x * blockDim.x;
    for (; i < E; i += stride) atomicAdd(&cnt[eidx[i]], 1);
}

__global__ __launch_bounds__(256) void k_scan(const int* __restrict__ cnt,
                                              int* __restrict__ offs,
                                              int* __restrict__ cur, int N) {
    __shared__ int part[256];
    const int t = threadIdx.x;
    const int chunk = (N + 255) / 256;
    int s = 0;
    for (int k = 0; k < chunk; ++k) {
        const int i = t * chunk + k;
        if (i < N) s += cnt[i];
    }
    part[t] = s;
    __syncthreads();
    for (int d = 1; d < 256; d <<= 1) {
        const int v = (t >= d) ? part[t - d] : 0;
        __syncthreads();
        part[t] += v;
        __syncthreads();
    }
    int base = (t == 0) ? 0 : part[t - 1];
    for (int k = 0; k < chunk; ++k) {
        const int i = t * chunk + k;
        if (i < N) { offs[i] = base; cur[i] = base; base += cnt[i]; }
    }
    if (t == 255) offs[N] = part[255];
}

__global__ void k_scatter(const int* __restrict__ eidx, int* __restrict__ cur,
                          int* __restrict__ elist, int E) {
    int i = blockIdx.x * blockDim.x + threadIdx.x;
    const int stride = gridDim.x * blockDim.x;
    for (; i < E; i += stride) {
        const int p = atomicAdd(&cur[eidx[i]], 1);
        elist[p] = i;
    }
}

// ---------------- fused weight pack ----------------
__global__ __launch_bounds__(256) void k_packall(
    const float* __restrict__ W_lin, const float* __restrict__ b_lin,
    const float* __restrict__ Wa1, const float* __restrict__ ba1,
    const float* __restrict__ We1, const float* __restrict__ be1,
    const float* __restrict__ We2,
    const float* __restrict__ Wn1, const float* __restrict__ bn1,
    const float* __restrict__ Wn2,
    const float* __restrict__ Wc1, const float* __restrict__ bc1,
    const float* __restrict__ Wc2,
    ushort* __restrict__ pack) {
    const int b = blockIdx.x, t = threadIdx.x;
    const float* W = nullptr; const float* bias = nullptr;
    int kbase = 0, fold = 0, ext = 0, nW = 0;
    if (b < 5)       { W = W_lin; bias = b_lin; if (b == 4) { ext = 1; nW = 0; } else kbase = b * 32; }
    else if (b < 14) { int k = b - 5;  W = Wa1; bias = ba1; if (k == 8) { ext = 1; nW = 3; kbase = 256; } else { kbase = k * 32; fold = (k < 4); } }
    else if (b < 19) { int k = b - 14; W = We1; bias = be1; if (k == 4) { ext = 1; nW = 3; kbase = 128; } else kbase = k * 32; }
    else if (b < 23) { W = We2; kbase = (b - 19) * 32; }
    else if (b < 28) { int k = b - 23; W = Wn1; bias = bn1; if (k == 4) { ext = 1; nW = 0; } else kbase = k * 32; }
    else if (b < 32) { W = Wn2; kbase = (b - 28) * 32; }
    else if (b < 41) { int k = b - 32; W = Wc1; bias = bc1; if (k == 8) { ext = 1; nW = 3; kbase = 256; } else kbase = k * 32; }
    else             { W = Wc2; kbase = (b - 41) * 32; }
    ushort* dst = pack + (size_t)b * 4096;
#pragma unroll
    for (int i = 0; i < 16; ++i) {
        const int e = t + 256 * i;
        const int j = e & 7, lane = (e >> 3) & 63, nt = e >> 9;
        const int kl = (lane >> 4) * 8 + j;
        const int n = nt * 16 + (lane & 15);
        float v;
        if (!ext) {
            v = W[(kbase + kl) * D + n];
            if (fold) v += W[(kbase + kl + 128) * D + n];
        } else {
            v = (kl < nW) ? W[(kbase + kl) * D + n] : (kl == nW ? bias[n] : 0.0f);
        }
        dst[e] = f2bs(v);
    }
}

// ---------------- node_lin: hh = h @ W_lin + b (MFMA, 64 nodes/block) ----------------
__global__ __launch_bounds__(256) void k_node_lin(
    const float* __restrict__ h, const ushort* __restrict__ pack,
    float* __restrict__ hh, ushort* __restrict__ hh1b, int N) {
    __shared__ ushort hs[64][RS];
    const int t = threadIdx.x, lane = t & 63, wave = t >> 6;
    const int quad = lane >> 4, l16 = lane & 15;
    const int mh = wave >> 1, nh = wave & 1;
    const int base = blockIdx.x * 64;

#pragma unroll
    for (int q = 0; q < 8; ++q) {
        const int f = t + 256 * q;
        const int row = f >> 5, c4 = (f & 31) << 2;
        const int node = base + row;
        float4 v = make_float4(0.f, 0.f, 0.f, 0.f);
        if (node < N) v = *(const float4*)(h + (size_t)node * D + c4);
        *(uint2*)&hs[row][c4] = make_uint2(pkbf(v.x, v.y), pkbf(v.z, v.w));
    }
    __syncthreads();

    short8 aext = (short8)0;
    if (quad == 0) aext[0] = (short)0x3F80;

    f32x4 acc[2][4] = {};
    const short8* pB = (const short8*)(pack + (size_t)PWLIN * 4096);
#pragma unroll
    for (int ks = 0; ks < 5; ++ks) {
        short8 bfr[4];
#pragma unroll
        for (int nt = 0; nt < 4; ++nt) bfr[nt] = pB[(ks * 8 + nh * 4 + nt) * 64 + lane];
#pragma unroll
        for (int mt = 0; mt < 2; ++mt) {
            const short8 a = (ks < 4) ? *(const short8*)&hs[mh * 32 + mt * 16 + l16][ks * 32 + quad * 8]
                                      : aext;
#pragma unroll
            for (int nt = 0; nt < 4; ++nt) acc[mt][nt] = MFMA16(a, bfr[nt], acc[mt][nt]);
        }
    }
#pragma unroll
    for (int mt = 0; mt < 2; ++mt)
#pragma unroll
        for (int reg = 0; reg < 4; ++reg) {
            const int g = base + mh * 32 + mt * 16 + quad * 4 + reg;
            if (g < N) {
#pragma unroll
                for (int nt = 0; nt < 4; ++nt) {
                    const int col = nh * 64 + nt * 16 + l16;
                    const float v = acc[mt][nt][reg];
                    hh[(size_t)g * D + col] = v;
                    hh1b[(size_t)g * D + col] = f2bs(v);
                }
            }
        }
}

// ---------------- edge phase 1 (CSR order): att + msg -> agg segmented ----------------
__global__ __launch_bounds__(256) void k_edge1(
    const int* __restrict__ eidx, const float* __restrict__ x,
    const float* __restrict__ eattr, const float* __restrict__ emask,
    const ushort* __restrict__ hh1b, const ushort* __restrict__ pack,
    const float* __restrict__ Wa2f, const float* __restrict__ ba2f,
    const float* __restrict__ be2f, const int* __restrict__ elist,
    float* __restrict__ agg, float2* __restrict__ e3buf, int E) {
    __shared__ ushort hr_s[32][RS];   // hr; m1 overlay after GEMM1
    __shared__ ushort d_s[32][RS];    // hc - hr; msg overlay after GEMM3
    __shared__ float dist_s[32], attr_s[32], geo_s[32], att_s[32], em_s[32];
    __shared__ int node_s[32], col_s[32];
    __shared__ float attp_s[4][32];

    const int t = threadIdx.x, lane = t & 63, w = t >> 6;
    const int quad = lane >> 4, l16 = lane & 15;
    const int base = blockIdx.x * 32;

    if (t < 32) {
        const int i = base + t;
        int r = 0, c = 0; float dist = 0.f, at = 0.f, em = 0.f;
        if (i < E) {
            const int e = elist[i];
            r = eidx[e]; c = eidx[E + e];
            const float dx = x[r * 3 + 0] - x[c * 3 + 0];
            const float dy = x[r * 3 + 1] - x[c * 3 + 1];
            const float dz = x[r * 3 + 2] - x[c * 3 + 2];
            dist = sqrtf(dx * dx + dy * dy + dz * dz + 1e-8f);
            at = eattr[e]; em = emask[e];
        }
        node_s[t] = r; col_s[t] = c;
        dist_s[t] = dist; attr_s[t] = at; em_s[t] = em;   // em=0 for invalid -> msg=0
    }
    float wa2[2], b3[2];
#pragma unroll
    for (int nt = 0; nt < 2; ++nt) {
        const int col = w * 32 + nt * 16 + l16;
        wa2[nt] = Wa2f[col]; b3[nt] = be2f[col];
    }
    __syncthreads();

    // gather hr, build d = hc - hr, geo  (CSR order -> hr rows L1-local)
    {
        const int g = t >> 4;
#pragma unroll
        for (int it = 0; it < 2; ++it) {
            const int e = g * 2 + it;
            const uint4 vr = *(const uint4*)(hh1b + (size_t)node_s[e] * D + l16 * 8);
            const uint4 vc = *(const uint4*)(hh1b + (size_t)col_s[e] * D + l16 * 8);
            *(uint4*)&hr_s[e][l16 * 8] = vr;
            const unsigned* pr = (const unsigned*)&vr;
            const unsigned* pc = (const unsigned*)&vc;
            float s = 0.f; unsigned dw[4];
#pragma unroll
            for (int q = 0; q < 4; ++q) {
                const float r0 = __uint_as_float(pr[q] << 16), r1 = __uint_as_float(pr[q] & 0xffff0000u);
                const float c0 = __uint_as_float(pc[q] << 16), c1 = __uint_as_float(pc[q] & 0xffff0000u);
                const float d0 = c0 - r0, d1 = c1 - r1;
                s += d0 * d0 + d1 * d1;
                dw[q] = pkbf(d0, d1);
            }
            *(uint4*)&d_s[e][l16 * 8] = make_uint4(dw[0], dw[1], dw[2], dw[3]);
            s += __shfl_xor(s, 1); s += __shfl_xor(s, 2); s += __shfl_xor(s, 4); s += __shfl_xor(s, 8);
            if (l16 == 0) {
                const float gg = sqrtf(s + 1e-8f);
                geo_s[e] = gg;
                if (base + e < E) e3buf[base + e] = make_float2(dist_s[e], gg);  // CSR position
            }
        }
    }
    __syncthreads();

    short8 aext[2];
#pragma unroll
    for (int mt = 0; mt < 2; ++mt) {
        short8 v = (short8)0;
        if (quad == 0) {
            const int m = mt * 16 + l16;
            v[0] = (short)f2bs(dist_s[m]); v[1] = (short)f2bs(attr_s[m]);
            v[2] = (short)f2bs(geo_s[m]);  v[3] = (short)0x3F80;
        }
        aext[mt] = v;
    }

    // GEMM1: a1 = silu(hr@(Wr+Wc) + d@Wc + ext); att partials
    {
        f32x4 acc[2][2] = {};
        const short8* pB = (const short8*)(pack + (size_t)PWA1 * 4096);
#pragma unroll
        for (int ks = 0; ks < 9; ++ks) {
            short8 b0 = pB[(ks * 8 + w * 2 + 0) * 64 + lane];
            short8 b1 = pB[(ks * 8 + w * 2 + 1) * 64 + lane];
#pragma unroll
            for (int mt = 0; mt < 2; ++mt) {
                const short8 a = (ks < 4) ? *(const short8*)&hr_s[mt * 16 + l16][ks * 32 + quad * 8]
                               : (ks < 8) ? *(const short8*)&d_s[mt * 16 + l16][(ks - 4) * 32 + quad * 8]
                                          : aext[mt];
                acc[mt][0] = MFMA16(a, b0, acc[mt][0]);
                acc[mt][1] = MFMA16(a, b1, acc[mt][1]);
            }
        }
#pragma unroll
        for (int mt = 0; mt < 2; ++mt)
#pragma unroll
            for (int reg = 0; reg < 4; ++reg) {
                float p = siluf(acc[mt][0][reg]) * wa2[0] + siluf(acc[mt][1][reg]) * wa2[1];
                p += __shfl_xor(p, 1); p += __shfl_xor(p, 2); p += __shfl_xor(p, 4); p += __shfl_xor(p, 8);
                if (l16 == 0) attp_s[w][mt * 16 + quad * 4 + reg] = p;
            }
    }
    __syncthreads();   // attp ready; GEMM1 LDS reads done

    if (t < 32)
        att_s[t] = sigmf(attp_s[0][t] + attp_s[1][t] + attp_s[2][t] + attp_s[3][t] + ba2f[0]) * em_s[t];

    // GEMM2: m1 = silu(d@We1 + ext) -> bf16 overlay into hr_s
    {
        f32x4 acc[2][2] = {};
        const short8* pB = (const short8*)(pack + (size_t)PWE1 * 4096);
#pragma unroll
        for (int ks = 0; ks < 5; ++ks) {
            short8 b0 = pB[(ks * 8 + w * 2 + 0) * 64 + lane];
            short8 b1 = pB[(ks * 8 + w * 2 + 1) * 64 + lane];
#pragma unroll
            for (int mt = 0; mt < 2; ++mt) {
                const short8 a = (ks < 4) ? *(const short8*)&d_s[mt * 16 + l16][ks * 32 + quad * 8]
                                          : aext[mt];
                acc[mt][0] = MFMA16(a, b0, acc[mt][0]);
                acc[mt][1] = MFMA16(a, b1, acc[mt][1]);
            }
        }
#pragma unroll
        for (int mt = 0; mt < 2; ++mt)
#pragma unroll
            for (int reg = 0; reg < 4; ++reg) {
                const int row = mt * 16 + quad * 4 + reg;
#pragma unroll
                for (int nt = 0; nt < 2; ++nt)
                    hr_s[row][w * 32 + nt * 16 + l16] = f2bs(siluf(acc[mt][nt][reg]));
            }
    }
    __syncthreads();   // m1 + att ready; d_s reads done

    // GEMM3: msg = (m1@We2 + be2) * att -> bf16 into d_s overlay
    {
        f32x4 acc[2][2] = {};
        const short8* pB = (const short8*)(pack + (size_t)PWE2 * 4096);
#pragma unroll
        for (int ks = 0; ks < 4; ++ks) {
            short8 b0 = pB[(ks * 8 + w * 2 + 0) * 64 + lane];
            short8 b1 = pB[(ks * 8 + w * 2 + 1) * 64 + lane];
#pragma unroll
            for (int mt = 0; mt < 2; ++mt) {
                const short8 a = *(const short8*)&hr_s[mt * 16 + l16][ks * 32 + quad * 8];
                acc[mt][0] = MFMA16(a, b0, acc[mt][0]);
                acc[mt][1] = MFMA16(a, b1, acc[mt][1]);
            }
        }
#pragma unroll
        for (int mt = 0; mt < 2; ++mt)
#pragma unroll
            for (int reg = 0; reg < 4; ++reg) {
                const int row = mt * 16 + quad * 4 + reg;
                const float av = att_s[row];
#pragma unroll
                for (int nt = 0; nt < 2; ++nt)
                    d_s[row][w * 32 + nt * 16 + l16] = f2bs((acc[mt][nt][reg] + b3[nt]) * av);
            }
    }
    __syncthreads();

    // segmented reduction over CSR-sorted node ids: ~1.5 flushes per 16-edge half
    {
        const int j = t & 127, h = t >> 7;
        float acc = 0.f;
        int rprev = node_s[h * 16];
#pragma unroll
        for (int k = 0; k < 16; ++k) {
            const int row = h * 16 + k;
            const int rn = node_s[row];
            if (rn != rprev) {
                atomicAdd(&agg[(size_t)rprev * D + j], acc);
                acc = 0.f; rprev = rn;
            }
            acc += bs2f(d_s[row][j]);
        }
        atomicAdd(&agg[(size_t)rprev * D + j], acc);
    }
}

// ---------------- node2: MLP + residual + LN + silu (MFMA, 64 nodes/block) ----------------
__global__ __launch_bounds__(256) void k_node2(
    const float* __restrict__ agg, float* hio,
    const ushort* __restrict__ pack,
    const float* __restrict__ bn2f,
    const float* __restrict__ ln_g, const float* __restrict__ ln_b,
    ushort* __restrict__ hh2b, int N) {
    __shared__ ushort ag_s[64][RS];
    __shared__ float redS[2][64], redQ[2][64];
    const int t = threadIdx.x, lane = t & 63, wave = t >> 6;
    const int quad = lane >> 4, l16 = lane & 15;
    const int mh = wave >> 1, nh = wave & 1;
    const int base = blockIdx.x * 64;

#pragma unroll
    for (int q = 0; q < 8; ++q) {
        const int f = t + 256 * q;
        const int row = f >> 5, c4 = (f & 31) << 2;
        const int node = base + row;
        float4 v = make_float4(0.f, 0.f, 0.f, 0.f);
        if (node < N) v = *(const float4*)(agg + (size_t)node * D + c4);
        *(uint2*)&ag_s[row][c4] = make_uint2(pkbf(v.x, v.y), pkbf(v.z, v.w));
    }
    float bn2[4], lg[4], lb[4];
#pragma unroll
    for (int nt = 0; nt < 4; ++nt) {
        const int col = nh * 64 + nt * 16 + l16;
        bn2[nt] = bn2f[col]; lg[nt] = ln_g[col]; lb[nt] = ln_b[col];
    }
    __syncthreads();

    short8 aext = (short8)0;
    if (quad == 0) aext[0] = (short)0x3F80;

    f32x4 acc[2][4] = {};
    {
        const short8* pB = (const short8*)(pack + (size_t)PWN1 * 4096);
#pragma unroll
        for (int ks = 0; ks < 5; ++ks) {
            short8 bfr[4];
#pragma unroll
            for (int nt = 0; nt < 4; ++nt) bfr[nt] = pB[(ks * 8 + nh * 4 + nt) * 64 + lane];
#pragma unroll
            for (int mt = 0; mt < 2; ++mt) {
                const short8 a = (ks < 4) ? *(const short8*)&ag_s[mh * 32 + mt * 16 + l16][ks * 32 + quad * 8]
                                          : aext;
#pragma unroll
                for (int nt = 0; nt < 4; ++nt) acc[mt][nt] = MFMA16(a, bfr[nt], acc[mt][nt]);
            }
        }
    }
    __syncthreads();
#pragma unroll
    for (int mt = 0; mt < 2; ++mt)
#pragma unroll
        for (int reg = 0; reg < 4; ++reg) {
            const int row = mh * 32 + mt * 16 + quad * 4 + reg;
#pragma unroll
            for (int nt = 0; nt < 4; ++nt)
                ag_s[row][nh * 64 + nt * 16 + l16] = f2bs(siluf(acc[mt][nt][reg]));
        }
    __syncthreads();

    {
        const short8* pB = (const short8*)(pack + (size_t)PWN2 * 4096);
#pragma unroll
        for (int mt = 0; mt < 2; ++mt)
#pragma unroll
            for (int nt = 0; nt < 4; ++nt) acc[mt][nt] = (f32x4)0.0f;
#pragma unroll
        for (int ks = 0; ks < 4; ++ks) {
            short8 bfr[4];
#pragma unroll
            for (int nt = 0; nt < 4; ++nt) bfr[nt] = pB[(ks * 8 + nh * 4 + nt) * 64 + lane];
#pragma unroll
            for (int mt = 0; mt < 2; ++mt) {
                const short8 a = *(const short8*)&ag_s[mh * 32 + mt * 16 + l16][ks * 32 + quad * 8];
#pragma unroll
                for (int nt = 0; nt < 4; ++nt) acc[mt][nt] = MFMA16(a, bfr[nt], acc[mt][nt]);
            }
        }
    }
#pragma unroll
    for (int mt = 0; mt < 2; ++mt)
#pragma unroll
        for (int reg = 0; reg < 4; ++reg) {
            const int row = mh * 32 + mt * 16 + quad * 4 + reg;
            const int g = base + row;
            float s = 0.f, qq = 0.f;
#pragma unroll
            for (int nt = 0; nt < 4; ++nt) {
                const int col = nh * 64 + nt * 16 + l16;
                float v = acc[mt][nt][reg] + bn2[nt];
                if (g < N) v += hio[(size_t)g * D + col];
                acc[mt][nt][reg] = v;
                s += v; qq += v * v;
            }
            s += __shfl_xor(s, 1); s += __shfl_xor(s, 2); s += __shfl_xor(s, 4); s += __shfl_xor(s, 8);
            qq += __shfl_xor(qq, 1); qq += __shfl_xor(qq, 2); qq += __shfl_xor(qq, 4); qq += __shfl_xor(qq, 8);
            if (l16 == 0) { redS[nh][row] = s; redQ[nh][row] = qq; }
        }
    __syncthreads();

#pragma unroll
    for (int mt = 0; mt < 2; ++mt)
#pragma unroll
        for (int reg = 0; reg < 4; ++reg) {
            const int row = mh * 32 + mt * 16 + quad * 4 + reg;
            const int g = base + row;
            const float mu = (redS[0][row] + redS[1][row]) * (1.0f / D);
            const float var = (redQ[0][row] + redQ[1][row]) * (1.0f / D) - mu * mu;
            const float rstd = rsqrtf(var + 1e-5f);
            if (g < N) {
#pragma unroll
                for (int nt = 0; nt < 4; ++nt) {
                    const int col = nh * 64 + nt * 16 + l16;
                    const float hn = (acc[mt][nt][reg] - mu) * rstd * lg[nt] + lb[nt];
                    const float o = siluf(hn);
                    hio[(size_t)g * D + col] = o;
                    hh2b[(size_t)g * D + col] = f2bs(o);
                }
            }
        }
}

// ---------------- edge phase 2 (CSR order): coord MLP -> aggx ----------------
__global__ __launch_bounds__(256) void k_edge2(
    const int* __restrict__ eidx, const float* __restrict__ x,
    const float* __restrict__ eattr, const float* __restrict__ emask,
    const ushort* __restrict__ hh2b, const ushort* __restrict__ pack,
    const float* __restrict__ bc2f, const float* __restrict__ Wc3f,
    const int* __restrict__ elist,
    const float2* __restrict__ e3buf, float* __restrict__ aggx, int E) {
    __shared__ ushort ar_s[32][RS];
    __shared__ ushort ac_s[32][RS];
    __shared__ float dist_s[32], attr_s[32], geo_s[32], em_s[32];
    __shared__ float cdx_s[32], cdy_s[32], cdz_s[32];
    __shared__ int node_s[32], col_s[32];
    __shared__ float mp_s[4][32];

    const int t = threadIdx.x, lane = t & 63, w = t >> 6;
    const int quad = lane >> 4, l16 = lane & 15;
    const int base = blockIdx.x * 32;

    if (t < 32) {
        const int i = base + t;
        int r = 0, c = 0;
        float dist = 1.f, geo = 0.f, at = 0.f, em = 0.f, cdx = 0.f, cdy = 0.f, cdz = 0.f;
        if (i < E) {
            const int e = elist[i];
            r = eidx[e]; c = eidx[E + e];
            const float2 dg = e3buf[i];
            dist = dg.x; geo = dg.y;
            at = eattr[e]; em = emask[e];
            const float inv = 1.0f / (dist + 1.0f);
            cdx = (x[r * 3 + 0] - x[c * 3 + 0]) * inv;
            cdy = (x[r * 3 + 1] - x[c * 3 + 1]) * inv;
            cdz = (x[r * 3 + 2] - x[c * 3 + 2]) * inv;
        }
        node_s[t] = r; col_s[t] = c;
        dist_s[t] = dist; geo_s[t] = geo; attr_s[t] = at; em_s[t] = em;
        cdx_s[t] = cdx; cdy_s[t] = cdy; cdz_s[t] = cdz;
    }
    float bc2[2], wc3[2];
#pragma unroll
    for (int nt = 0; nt < 2; ++nt) {
        const int col = w * 32 + nt * 16 + l16;
        bc2[nt] = bc2f[col]; wc3[nt] = Wc3f[col];
    }
    __syncthreads();

    {
        const int g = t >> 4;
#pragma unroll
        for (int it = 0; it < 2; ++it) {
            const int e = g * 2 + it;
            *(uint4*)&ar_s[e][l16 * 8] = *(const uint4*)(hh2b + (size_t)node_s[e] * D + l16 * 8);
            *(uint4*)&ac_s[e][l16 * 8] = *(const uint4*)(hh2b + (size_t)col_s[e] * D + l16 * 8);
        }
    }
    __syncthreads();

    short8 aext[2];
#pragma unroll
    for (int mt = 0; mt < 2; ++mt) {
        short8 v = (short8)0;
        if (quad == 0) {
            const int m = mt * 16 + l16;
            v[0] = (short)f2bs(dist_s[m]); v[1] = (short)f2bs(attr_s[m]);
            v[2] = (short)f2bs(geo_s[m]);  v[3] = (short)0x3F80;
        }
        aext[mt] = v;
    }

    // GEMM1: c1 = silu([h2r|h2c]@Wc1 + ext)
    {
        f32x4 acc[2][2] = {};
        const short8* pB = (const short8*)(pack + (size_t)PWC1 * 4096);
#pragma unroll
        for (int ks = 0; ks < 9; ++ks) {
            short8 b0 = pB[(ks * 8 + w * 2 + 0) * 64 + lane];
            short8 b1 = pB[(ks * 8 + w * 2 + 1) * 64 + lane];
#pragma unroll
            for (int mt = 0; mt < 2; ++mt) {
                const short8 a = (ks < 4) ? *(const short8*)&ar_s[mt * 16 + l16][ks * 32 + quad * 8]
                               : (ks < 8) ? *(const short8*)&ac_s[mt * 16 + l16][(ks - 4) * 32 + quad * 8]
                                          : aext[mt];
                acc[mt][0] = MFMA16(a, b0, acc[mt][0]);
                acc[mt][1] = MFMA16(a, b1, acc[mt][1]);
            }
        }
        __syncthreads();
#pragma unroll
        for (int mt = 0; mt < 2; ++mt)
#pragma unroll
            for (int reg = 0; reg < 4; ++reg) {
                const int row = mt * 16 + quad * 4 + reg;
#pragma unroll
                for (int nt = 0; nt < 2; ++nt)
                    ar_s[row][w * 32 + nt * 16 + l16] = f2bs(siluf(acc[mt][nt][reg]));
            }
    }
    __syncthreads();

    // GEMM2: c2 = silu(c1@Wc2 + bc2); m-partials over this wave's cols
    {
        f32x4 acc[2][2] = {};
        const short8* pB = (const short8*)(pack + (size_t)PWC2 * 4096);
#pragma unroll
        for (int ks = 0; ks < 4; ++ks) {
            short8 b0 = pB[(ks * 8 + w * 2 + 0) * 64 + lane];
            short8 b1 = pB[(ks * 8 + w * 2 + 1) * 64 + lane];
#pragma unroll
            for (int mt = 0; mt < 2; ++mt) {
                const short8 a = *(const short8*)&ar_s[mt * 16 + l16][ks * 32 + quad * 8];
                acc[mt][0] = MFMA16(a, b0, acc[mt][0]);
                acc[mt][1] = MFMA16(a, b1, acc[mt][1]);
            }
        }
#pragma unroll
        for (int mt = 0; mt < 2; ++mt)
#pragma unroll
            for (int reg = 0; reg < 4; ++reg) {
                float p = siluf(acc[mt][0][reg] + bc2[0]) * wc3[0]
                        + siluf(acc[mt][1][reg] + bc2[1]) * wc3[1];
                p += __shfl_xor(p, 1); p += __shfl_xor(p, 2); p += __shfl_xor(p, 4); p += __shfl_xor(p, 8);
                if (l16 == 0) mp_s[w][mt * 16 + quad * 4 + reg] = p;
            }
    }
    __syncthreads();

    if (t < 32 && base + t < E) {
        const float m = mp_s[0][t] + mp_s[1][t] + mp_s[2][t] + mp_s[3][t];
        const float tr = m * em_s[t];
        const int r4 = node_s[t] * 4;
        atomicAdd(&aggx[r4 + 0], cdx_s[t] * tr);
        atomicAdd(&aggx[r4 + 1], cdy_s[t] * tr);
        atomicAdd(&aggx[r4 + 2], cdz_s[t] * tr);
    }
}

// ---------------- coord epilogue ----------------
__global__ void k_coord(const float* __restrict__ x, const float* __restrict__ nmask,
                        const float* __restrict__ aggx, float* __restrict__ out_x, int N) {
    const int idx = blockIdx.x * blockDim.x + threadIdx.x;
    if (idx >= N * 3) return;
    const int i = idx / 3, d = idx - i * 3;
    out_x[idx] = (x[idx] + aggx[i * 4 + d] * (1.0f / 100.0f)) * nmask[i];
}

extern "C" void kernel_launch(void* const* d_in, const int* in_sizes, int n_in,
                              void* d_out, int out_size, void* d_ws, size_t ws_size,
                              hipStream_t stream) {
    const float* h     = (const float*)d_in[0];
    const float* x     = (const float*)d_in[1];
    const int*   eidx  = (const int*)d_in[2];
    const float* nmask = (const float*)d_in[3];
    const float* emask = (const float*)d_in[4];
    const float* eattr = (const float*)d_in[5];
    const float* W_lin = (const float*)d_in[6];
    const float* b_lin = (const float*)d_in[7];
    const float* We1   = (const float*)d_in[8];
    const float* be1   = (const float*)d_in[9];
    const float* We2   = (const float*)d_in[10];
    const float* be2   = (const float*)d_in[11];
    const float* Wn1   = (const float*)d_in[12];
    const float* bn1   = (const float*)d_in[13];
    const float* Wn2   = (const float*)d_in[14];
    const float* bn2   = (const float*)d_in[15];
    const float* Wa1   = (const float*)d_in[16];
    const float* ba1   = (const float*)d_in[17];
    const float* Wa2   = (const float*)d_in[18];
    const float* ba2   = (const float*)d_in[19];
    const float* ln_g  = (const float*)d_in[20];
    const float* ln_b  = (const float*)d_in[21];
    const float* Wc1   = (const float*)d_in[22];
    const float* bc1   = (const float*)d_in[23];
    const float* Wc2   = (const float*)d_in[24];
    const float* bc2   = (const float*)d_in[25];
    const float* Wc3   = (const float*)d_in[26];

    const int N = in_sizes[0] / D;
    const int E = in_sizes[2] / 2;

    // ws layout (256-B aligned regions), ~29 MB
    char* wp = (char*)d_ws;
    auto take = [&](size_t bytes) -> void* {
        void* p = wp; wp += (bytes + 255) & ~(size_t)255; return p;
    };
    float*  agg   = (float*)take((size_t)N * D * 4);   // zeroed
    float*  aggx  = (float*)take((size_t)N * 4 * 4);   // zeroed
    int*    cnt   = (int*)take((size_t)N * 4);         // zeroed
    int*    offs  = (int*)take((size_t)(N + 1) * 4);
    int*    cur   = (int*)take((size_t)N * 4);
    int*    elist = (int*)take((size_t)E * 4);
    float2* e3buf = (float2*)take((size_t)E * 8);
    ushort* hh1b  = (ushort*)take((size_t)N * D * 2);
    ushort* hh2b  = (ushort*)take((size_t)N * D * 2);
    ushort* pack  = (ushort*)take((size_t)NPACK * 4096 * 2);

    float* out_h = (float*)d_out;          // doubles as hh fp32 storage
    float* out_x = out_h + (size_t)N * D;

    const int EB = (E + 31) / 32;
    const int NB = (N + 63) / 64;

    // zero agg | aggx | cnt (contiguous only if pads are zero-length; zero each)
    k_zero<<<2048, 256, 0, stream>>>(agg, (long)N * D);
    k_zero<<<64, 256, 0, stream>>>(aggx, (long)N * 4);
    k_zero<<<64, 256, 0, stream>>>((float*)cnt, (long)N);
    k_packall<<<NPACK, 256, 0, stream>>>(W_lin, b_lin, Wa1, ba1, We1, be1, We2,
                                         Wn1, bn1, Wn2, Wc1, bc1, Wc2, pack);
    k_hist<<<1024, 256, 0, stream>>>(eidx, cnt, E);
    k_scan<<<1, 256, 0, stream>>>(cnt, offs, cur, N);
    k_scatter<<<1024, 256, 0, stream>>>(eidx, cur, elist, E);
    k_node_lin<<<NB, 256, 0, stream>>>(h, pack, out_h, hh1b, N);
    k_edge1<<<EB, 256, 0, stream>>>(eidx, x, eattr, emask, hh1b, pack,
                                    Wa2, ba2, be2, elist, agg, e3buf, E);
    k_node2<<<NB, 256, 0, stream>>>(agg, out_h, pack, bn2, ln_g, ln_b, hh2b, N);
    k_edge2<<<EB, 256, 0, stream>>>(eidx, x, eattr, emask, hh2b, pack,
                                    bc2, Wc3, elist, e3buf, aggx, E);
    k_coord<<<(N * 3 + 255) / 256, 256, 0, stream>>>(x, nmask, aggx, out_x, N);
}

// Round 7
// 622.269 us; speedup vs baseline: 1.2102x; 1.2102x over previous
//
#include <hip/hip_runtime.h>
#include <hip/hip_bf16.h>

// EquivariantBlock — Round 7.
// R6 regression diagnosed: elist indirection turned eidx/eattr/emask reads into
// random 64B-line gathers (FETCH 67->194MB per edge kernel; latency-bound, no pipe
// >40%). Fix: k_scatter_build writes CSR-ordered SoA edge records (row/col/dist,
// attr/em) so edge kernels read sequentially; geo passed via float[E]; edge1's
// a1/m1 GEMMs fused into one K-loop (shared d/ext A-fragments); edge2 aggx via
// segmented reduce (kills same-address atomic contention CSR introduced).

#define D 128
#define RS 136          // LDS row stride in bf16 units (128 + 8 pad)

typedef unsigned short ushort;
typedef __attribute__((ext_vector_type(8))) short short8;
typedef __attribute__((ext_vector_type(4))) float f32x4;

__device__ __forceinline__ float siluf(float x) { return x / (1.0f + __expf(-x)); }
__device__ __forceinline__ float sigmf(float x) { return 1.0f / (1.0f + __expf(-x)); }
__device__ __forceinline__ ushort f2bs(float f) {
    __hip_bfloat16 b = __float2bfloat16(f);
    ushort u; __builtin_memcpy(&u, &b, 2); return u;
}
__device__ __forceinline__ unsigned pkbf(float lo, float hi) {
    __hip_bfloat162 h2 = __float22bfloat162_rn(make_float2(lo, hi));
    unsigned u; __builtin_memcpy(&u, &h2, 4); return u;
}
__device__ __forceinline__ float bs2f(ushort u) {
    return __uint_as_float(((unsigned)u) << 16);
}
#define MFMA16(a, b, c) __builtin_amdgcn_mfma_f32_16x16x32_bf16((a), (b), (c), 0, 0, 0)

// packed-weight block offsets (units of 4096 ushorts)
#define PWLIN 0
#define PWA1  5
#define PWE1  14
#define PWE2  19
#define PWN1  23
#define PWN2  28
#define PWC1  32
#define PWC2  41
#define NPACK 45

// ---------------- zero scratch ----------------
__global__ void k_zero(float* __restrict__ p, long n) {
    long i = (long)blockIdx.x * blockDim.x + threadIdx.x;
    long stride = (long)gridDim.x * blockDim.x;
    for (; i < n; i += stride) p[i] = 0.0f;
}

// ---------------- CSR build ----------------
__global__ void k_hist(const int* __restrict__ eidx, int* __restrict__ cnt, int E) {
    int i = blockIdx.x * blockDim.x + threadIdx.x;
    const int stride = gridDim.x * blockDim.x;
    for (; i < E; i += stride) atomicAdd(&cnt[eidx[i]], 1);
}

__global__ __launch_bounds__(256) void k_scan(const int* __restrict__ cnt,
                                              int* __restrict__ cur, int N) {
    __shared__ int part[256];
    const int t = threadIdx.x;
    const int chunk = (N + 255) / 256;
    int s = 0;
    for (int k = 0; k < chunk; ++k) {
        const int i = t * chunk + k;
        if (i < N) s += cnt[i];
    }
    part[t] = s;
    __syncthreads();
    for (int d = 1; d < 256; d <<= 1) {
        const int v = (t >= d) ? part[t - d] : 0;
        __syncthreads();
        part[t] += v;
        __syncthreads();
    }
    int base = (t == 0) ? 0 : part[t - 1];
    for (int k = 0; k < chunk; ++k) {
        const int i = t * chunk + k;
        if (i < N) { cur[i] = base; base += cnt[i]; }
    }
}

// scatter + build CSR-ordered SoA edge records (sequential reads, scattered writes)
__global__ void k_scatter_build(
    const int* __restrict__ eidx, const float* __restrict__ x,
    const float* __restrict__ eattr, const float* __restrict__ emask,
    int* __restrict__ cur,
    int* __restrict__ ri, int* __restrict__ ci,
    float2* __restrict__ de, float* __restrict__ em, int E) {
    int i = blockIdx.x * blockDim.x + threadIdx.x;
    const int stride = gridDim.x * blockDim.x;
    for (; i < E; i += stride) {
        const int r = eidx[i], c = eidx[E + i];
        const int p = atomicAdd(&cur[r], 1);
        const float dx = x[r * 3 + 0] - x[c * 3 + 0];
        const float dy = x[r * 3 + 1] - x[c * 3 + 1];
        const float dz = x[r * 3 + 2] - x[c * 3 + 2];
        const float dist = sqrtf(dx * dx + dy * dy + dz * dz + 1e-8f);
        ri[p] = r; ci[p] = c;
        de[p] = make_float2(dist, eattr[i]);
        em[p] = emask[i];
    }
}

// ---------------- fused weight pack ----------------
__global__ __launch_bounds__(256) void k_packall(
    const float* __restrict__ W_lin, const float* __restrict__ b_lin,
    const float* __restrict__ Wa1, const float* __restrict__ ba1,
    const float* __restrict__ We1, const float* __restrict__ be1,
    const float* __restrict__ We2,
    const float* __restrict__ Wn1, const float* __restrict__ bn1,
    const float* __restrict__ Wn2,
    const float* __restrict__ Wc1, const float* __restrict__ bc1,
    const float* __restrict__ Wc2,
    ushort* __restrict__ pack) {
    const int b = blockIdx.x, t = threadIdx.x;
    const float* W = nullptr; const float* bias = nullptr;
    int kbase = 0, fold = 0, ext = 0, nW = 0;
    if (b < 5)       { W = W_lin; bias = b_lin; if (b == 4) { ext = 1; nW = 0; } else kbase = b * 32; }
    else if (b < 14) { int k = b - 5;  W = Wa1; bias = ba1; if (k == 8) { ext = 1; nW = 3; kbase = 256; } else { kbase = k * 32; fold = (k < 4); } }
    else if (b < 19) { int k = b - 14; W = We1; bias = be1; if (k == 4) { ext = 1; nW = 3; kbase = 128; } else kbase = k * 32; }
    else if (b < 23) { W = We2; kbase = (b - 19) * 32; }
    else if (b < 28) { int k = b - 23; W = Wn1; bias = bn1; if (k == 4) { ext = 1; nW = 0; } else kbase = k * 32; }
    else if (b < 32) { W = Wn2; kbase = (b - 28) * 32; }
    else if (b < 41) { int k = b - 32; W = Wc1; bias = bc1; if (k == 8) { ext = 1; nW = 3; kbase = 256; } else kbase = k * 32; }
    else             { W = Wc2; kbase = (b - 41) * 32; }
    ushort* dst = pack + (size_t)b * 4096;
#pragma unroll
    for (int i = 0; i < 16; ++i) {
        const int e = t + 256 * i;
        const int j = e & 7, lane = (e >> 3) & 63, nt = e >> 9;
        const int kl = (lane >> 4) * 8 + j;
        const int n = nt * 16 + (lane & 15);
        float v;
        if (!ext) {
            v = W[(kbase + kl) * D + n];
            if (fold) v += W[(kbase + kl + 128) * D + n];
        } else {
            v = (kl < nW) ? W[(kbase + kl) * D + n] : (kl == nW ? bias[n] : 0.0f);
        }
        dst[e] = f2bs(v);
    }
}

// ---------------- node_lin: hh = h @ W_lin + b (MFMA, 64 nodes/block) ----------------
__global__ __launch_bounds__(256) void k_node_lin(
    const float* __restrict__ h, const ushort* __restrict__ pack,
    float* __restrict__ hh, ushort* __restrict__ hh1b, int N) {
    __shared__ ushort hs[64][RS];
    const int t = threadIdx.x, lane = t & 63, wave = t >> 6;
    const int quad = lane >> 4, l16 = lane & 15;
    const int mh = wave >> 1, nh = wave & 1;
    const int base = blockIdx.x * 64;

#pragma unroll
    for (int q = 0; q < 8; ++q) {
        const int f = t + 256 * q;
        const int row = f >> 5, c4 = (f & 31) << 2;
        const int node = base + row;
        float4 v = make_float4(0.f, 0.f, 0.f, 0.f);
        if (node < N) v = *(const float4*)(h + (size_t)node * D + c4);
        *(uint2*)&hs[row][c4] = make_uint2(pkbf(v.x, v.y), pkbf(v.z, v.w));
    }
    __syncthreads();

    short8 aext = (short8)0;
    if (quad == 0) aext[0] = (short)0x3F80;

    f32x4 acc[2][4] = {};
    const short8* pB = (const short8*)(pack + (size_t)PWLIN * 4096);
#pragma unroll
    for (int ks = 0; ks < 5; ++ks) {
        short8 bfr[4];
#pragma unroll
        for (int nt = 0; nt < 4; ++nt) bfr[nt] = pB[(ks * 8 + nh * 4 + nt) * 64 + lane];
#pragma unroll
        for (int mt = 0; mt < 2; ++mt) {
            const short8 a = (ks < 4) ? *(const short8*)&hs[mh * 32 + mt * 16 + l16][ks * 32 + quad * 8]
                                      : aext;
#pragma unroll
            for (int nt = 0; nt < 4; ++nt) acc[mt][nt] = MFMA16(a, bfr[nt], acc[mt][nt]);
        }
    }
#pragma unroll
    for (int mt = 0; mt < 2; ++mt)
#pragma unroll
        for (int reg = 0; reg < 4; ++reg) {
            const int g = base + mh * 32 + mt * 16 + quad * 4 + reg;
            if (g < N) {
#pragma unroll
                for (int nt = 0; nt < 4; ++nt) {
                    const int col = nh * 64 + nt * 16 + l16;
                    const float v = acc[mt][nt][reg];
                    hh[(size_t)g * D + col] = v;
                    hh1b[(size_t)g * D + col] = f2bs(v);
                }
            }
        }
}

// ---------------- edge phase 1 (CSR records): fused a1/m1 K-loop ----------------
__global__ __launch_bounds__(256) void k_edge1(
    const int* __restrict__ ri, const int* __restrict__ ci,
    const float2* __restrict__ de, const float* __restrict__ em,
    const ushort* __restrict__ hh1b, const ushort* __restrict__ pack,
    const float* __restrict__ Wa2f, const float* __restrict__ ba2f,
    const float* __restrict__ be2f,
    float* __restrict__ agg, float* __restrict__ geo_c, int E) {
    __shared__ ushort hr_s[32][RS];   // hr; m1 overlay for GEMM3
    __shared__ ushort d_s[32][RS];    // hc - hr; msg overlay after GEMM3
    __shared__ float dist_s[32], attr_s[32], geo_s[32], att_s[32], em_s[32];
    __shared__ int node_s[32], col_s[32];
    __shared__ float attp_s[4][32];

    const int t = threadIdx.x, lane = t & 63, w = t >> 6;
    const int quad = lane >> 4, l16 = lane & 15;
    const int base = blockIdx.x * 32;

    if (t < 32) {
        const int i = base + t;
        int r = 0, c = 0; float dist = 0.f, at = 0.f, emv = 0.f;
        if (i < E) {
            r = ri[i]; c = ci[i];
            const float2 da = de[i];
            dist = da.x; at = da.y;
            emv = em[i];
        }
        node_s[t] = r; col_s[t] = c;
        dist_s[t] = dist; attr_s[t] = at; em_s[t] = emv;
    }
    float wa2[2], b3[2];
#pragma unroll
    for (int nt = 0; nt < 2; ++nt) {
        const int col = w * 32 + nt * 16 + l16;
        wa2[nt] = Wa2f[col]; b3[nt] = be2f[col];
    }
    __syncthreads();

    // gather hr, build d = hc - hr, geo
    {
        const int g = t >> 4;
#pragma unroll
        for (int it = 0; it < 2; ++it) {
            const int e = g * 2 + it;
            const uint4 vr = *(const uint4*)(hh1b + (size_t)node_s[e] * D + l16 * 8);
            const uint4 vc = *(const uint4*)(hh1b + (size_t)col_s[e] * D + l16 * 8);
            *(uint4*)&hr_s[e][l16 * 8] = vr;
            const unsigned* pr = (const unsigned*)&vr;
            const unsigned* pc = (const unsigned*)&vc;
            float s = 0.f; unsigned dw[4];
#pragma unroll
            for (int q = 0; q < 4; ++q) {
                const float r0 = __uint_as_float(pr[q] << 16), r1 = __uint_as_float(pr[q] & 0xffff0000u);
                const float c0 = __uint_as_float(pc[q] << 16), c1 = __uint_as_float(pc[q] & 0xffff0000u);
                const float d0 = c0 - r0, d1 = c1 - r1;
                s += d0 * d0 + d1 * d1;
                dw[q] = pkbf(d0, d1);
            }
            *(uint4*)&d_s[e][l16 * 8] = make_uint4(dw[0], dw[1], dw[2], dw[3]);
            s += __shfl_xor(s, 1); s += __shfl_xor(s, 2); s += __shfl_xor(s, 4); s += __shfl_xor(s, 8);
            if (l16 == 0) {
                const float gg = sqrtf(s + 1e-8f);
                geo_s[e] = gg;
                if (base + e < E) geo_c[base + e] = gg;
            }
        }
    }
    __syncthreads();

    short8 aext[2];
#pragma unroll
    for (int mt = 0; mt < 2; ++mt) {
        short8 v = (short8)0;
        if (quad == 0) {
            const int m = mt * 16 + l16;
            v[0] = (short)f2bs(dist_s[m]); v[1] = (short)f2bs(attr_s[m]);
            v[2] = (short)f2bs(geo_s[m]);  v[3] = (short)0x3F80;
        }
        aext[mt] = v;
    }

    // Fused K-loop: a1 = [hr(0-3)|d(4-7)|ext(8)] @ pWa1 ; m1 = [d|ext] @ pWe1
    f32x4 accA[2][2] = {}, accM[2][2] = {};
    {
        const short8* pA = (const short8*)(pack + (size_t)PWA1 * 4096);
        const short8* pM = (const short8*)(pack + (size_t)PWE1 * 4096);
#pragma unroll
        for (int ks = 0; ks < 9; ++ks) {
            const short8 bA0 = pA[(ks * 8 + w * 2 + 0) * 64 + lane];
            const short8 bA1 = pA[(ks * 8 + w * 2 + 1) * 64 + lane];
            short8 bM0 = (short8)0, bM1 = (short8)0;
            if (ks >= 4) {
                bM0 = pM[((ks - 4) * 8 + w * 2 + 0) * 64 + lane];
                bM1 = pM[((ks - 4) * 8 + w * 2 + 1) * 64 + lane];
            }
#pragma unroll
            for (int mt = 0; mt < 2; ++mt) {
                const short8 a = (ks < 4) ? *(const short8*)&hr_s[mt * 16 + l16][ks * 32 + quad * 8]
                               : (ks < 8) ? *(const short8*)&d_s[mt * 16 + l16][(ks - 4) * 32 + quad * 8]
                                          : aext[mt];
                accA[mt][0] = MFMA16(a, bA0, accA[mt][0]);
                accA[mt][1] = MFMA16(a, bA1, accA[mt][1]);
                if (ks >= 4) {
                    accM[mt][0] = MFMA16(a, bM0, accM[mt][0]);
                    accM[mt][1] = MFMA16(a, bM1, accM[mt][1]);
                }
            }
        }
    }
    // att partials from accA
#pragma unroll
    for (int mt = 0; mt < 2; ++mt)
#pragma unroll
        for (int reg = 0; reg < 4; ++reg) {
            float p = siluf(accA[mt][0][reg]) * wa2[0] + siluf(accA[mt][1][reg]) * wa2[1];
            p += __shfl_xor(p, 1); p += __shfl_xor(p, 2); p += __shfl_xor(p, 4); p += __shfl_xor(p, 8);
            if (l16 == 0) attp_s[w][mt * 16 + quad * 4 + reg] = p;
        }
    __syncthreads();   // attp ready; all K-loop LDS reads done

    if (t < 32)
        att_s[t] = sigmf(attp_s[0][t] + attp_s[1][t] + attp_s[2][t] + attp_s[3][t] + ba2f[0]) * em_s[t];
    // m1 overlay into hr_s
#pragma unroll
    for (int mt = 0; mt < 2; ++mt)
#pragma unroll
        for (int reg = 0; reg < 4; ++reg) {
            const int row = mt * 16 + quad * 4 + reg;
#pragma unroll
            for (int nt = 0; nt < 2; ++nt)
                hr_s[row][w * 32 + nt * 16 + l16] = f2bs(siluf(accM[mt][nt][reg]));
        }
    __syncthreads();   // m1 + att ready

    // GEMM3: msg = (m1@We2 + be2) * att -> bf16 into d_s overlay
    {
        f32x4 acc[2][2] = {};
        const short8* pB = (const short8*)(pack + (size_t)PWE2 * 4096);
#pragma unroll
        for (int ks = 0; ks < 4; ++ks) {
            const short8 b0 = pB[(ks * 8 + w * 2 + 0) * 64 + lane];
            const short8 b1 = pB[(ks * 8 + w * 2 + 1) * 64 + lane];
#pragma unroll
            for (int mt = 0; mt < 2; ++mt) {
                const short8 a = *(const short8*)&hr_s[mt * 16 + l16][ks * 32 + quad * 8];
                acc[mt][0] = MFMA16(a, b0, acc[mt][0]);
                acc[mt][1] = MFMA16(a, b1, acc[mt][1]);
            }
        }
#pragma unroll
        for (int mt = 0; mt < 2; ++mt)
#pragma unroll
            for (int reg = 0; reg < 4; ++reg) {
                const int row = mt * 16 + quad * 4 + reg;
                const float av = att_s[row];
#pragma unroll
                for (int nt = 0; nt < 2; ++nt)
                    d_s[row][w * 32 + nt * 16 + l16] = f2bs((acc[mt][nt][reg] + b3[nt]) * av);
            }
    }
    __syncthreads();

    // segmented reduction over CSR-sorted node ids
    {
        const int j = t & 127, h = t >> 7;
        float acc = 0.f;
        int rprev = node_s[h * 16];
#pragma unroll
        for (int k = 0; k < 16; ++k) {
            const int row = h * 16 + k;
            const int rn = node_s[row];
            if (rn != rprev) {
                atomicAdd(&agg[(size_t)rprev * D + j], acc);
                acc = 0.f; rprev = rn;
            }
            acc += bs2f(d_s[row][j]);
        }
        atomicAdd(&agg[(size_t)rprev * D + j], acc);
    }
}

// ---------------- node2: MLP + residual + LN + silu (MFMA, 64 nodes/block) ----------------
__global__ __launch_bounds__(256) void k_node2(
    const float* __restrict__ agg, float* hio,
    const ushort* __restrict__ pack,
    const float* __restrict__ bn2f,
    const float* __restrict__ ln_g, const float* __restrict__ ln_b,
    ushort* __restrict__ hh2b, int N) {
    __shared__ ushort ag_s[64][RS];
    __shared__ float redS[2][64], redQ[2][64];
    const int t = threadIdx.x, lane = t & 63, wave = t >> 6;
    const int quad = lane >> 4, l16 = lane & 15;
    const int mh = wave >> 1, nh = wave & 1;
    const int base = blockIdx.x * 64;

#pragma unroll
    for (int q = 0; q < 8; ++q) {
        const int f = t + 256 * q;
        const int row = f >> 5, c4 = (f & 31) << 2;
        const int node = base + row;
        float4 v = make_float4(0.f, 0.f, 0.f, 0.f);
        if (node < N) v = *(const float4*)(agg + (size_t)node * D + c4);
        *(uint2*)&ag_s[row][c4] = make_uint2(pkbf(v.x, v.y), pkbf(v.z, v.w));
    }
    float bn2[4], lg[4], lb[4];
#pragma unroll
    for (int nt = 0; nt < 4; ++nt) {
        const int col = nh * 64 + nt * 16 + l16;
        bn2[nt] = bn2f[col]; lg[nt] = ln_g[col]; lb[nt] = ln_b[col];
    }
    __syncthreads();

    short8 aext = (short8)0;
    if (quad == 0) aext[0] = (short)0x3F80;

    f32x4 acc[2][4] = {};
    {
        const short8* pB = (const short8*)(pack + (size_t)PWN1 * 4096);
#pragma unroll
        for (int ks = 0; ks < 5; ++ks) {
            short8 bfr[4];
#pragma unroll
            for (int nt = 0; nt < 4; ++nt) bfr[nt] = pB[(ks * 8 + nh * 4 + nt) * 64 + lane];
#pragma unroll
            for (int mt = 0; mt < 2; ++mt) {
                const short8 a = (ks < 4) ? *(const short8*)&ag_s[mh * 32 + mt * 16 + l16][ks * 32 + quad * 8]
                                          : aext;
#pragma unroll
                for (int nt = 0; nt < 4; ++nt) acc[mt][nt] = MFMA16(a, bfr[nt], acc[mt][nt]);
            }
        }
    }
    __syncthreads();
#pragma unroll
    for (int mt = 0; mt < 2; ++mt)
#pragma unroll
        for (int reg = 0; reg < 4; ++reg) {
            const int row = mh * 32 + mt * 16 + quad * 4 + reg;
#pragma unroll
            for (int nt = 0; nt < 4; ++nt)
                ag_s[row][nh * 64 + nt * 16 + l16] = f2bs(siluf(acc[mt][nt][reg]));
        }
    __syncthreads();

    {
        const short8* pB = (const short8*)(pack + (size_t)PWN2 * 4096);
#pragma unroll
        for (int mt = 0; mt < 2; ++mt)
#pragma unroll
            for (int nt = 0; nt < 4; ++nt) acc[mt][nt] = (f32x4)0.0f;
#pragma unroll
        for (int ks = 0; ks < 4; ++ks) {
            short8 bfr[4];
#pragma unroll
            for (int nt = 0; nt < 4; ++nt) bfr[nt] = pB[(ks * 8 + nh * 4 + nt) * 64 + lane];
#pragma unroll
            for (int mt = 0; mt < 2; ++mt) {
                const short8 a = *(const short8*)&ag_s[mh * 32 + mt * 16 + l16][ks * 32 + quad * 8];
#pragma unroll
                for (int nt = 0; nt < 4; ++nt) acc[mt][nt] = MFMA16(a, bfr[nt], acc[mt][nt]);
            }
        }
    }
#pragma unroll
    for (int mt = 0; mt < 2; ++mt)
#pragma unroll
        for (int reg = 0; reg < 4; ++reg) {
            const int row = mh * 32 + mt * 16 + quad * 4 + reg;
            const int g = base + row;
            float s = 0.f, qq = 0.f;
#pragma unroll
            for (int nt = 0; nt < 4; ++nt) {
                const int col = nh * 64 + nt * 16 + l16;
                float v = acc[mt][nt][reg] + bn2[nt];
                if (g < N) v += hio[(size_t)g * D + col];
                acc[mt][nt][reg] = v;
                s += v; qq += v * v;
            }
            s += __shfl_xor(s, 1); s += __shfl_xor(s, 2); s += __shfl_xor(s, 4); s += __shfl_xor(s, 8);
            qq += __shfl_xor(qq, 1); qq += __shfl_xor(qq, 2); qq += __shfl_xor(qq, 4); qq += __shfl_xor(qq, 8);
            if (l16 == 0) { redS[nh][row] = s; redQ[nh][row] = qq; }
        }
    __syncthreads();

#pragma unroll
    for (int mt = 0; mt < 2; ++mt)
#pragma unroll
        for (int reg = 0; reg < 4; ++reg) {
            const int row = mh * 32 + mt * 16 + quad * 4 + reg;
            const int g = base + row;
            const float mu = (redS[0][row] + redS[1][row]) * (1.0f / D);
            const float var = (redQ[0][row] + redQ[1][row]) * (1.0f / D) - mu * mu;
            const float rstd = rsqrtf(var + 1e-5f);
            if (g < N) {
#pragma unroll
                for (int nt = 0; nt < 4; ++nt) {
                    const int col = nh * 64 + nt * 16 + l16;
                    const float hn = (acc[mt][nt][reg] - mu) * rstd * lg[nt] + lb[nt];
                    const float o = siluf(hn);
                    hio[(size_t)g * D + col] = o;
                    hh2b[(size_t)g * D + col] = f2bs(o);
                }
            }
        }
}

// ---------------- edge phase 2 (CSR records): coord MLP -> aggx ----------------
__global__ __launch_bounds__(256) void k_edge2(
    const int* __restrict__ ri, const int* __restrict__ ci,
    const float2* __restrict__ de, const float* __restrict__ em,
    const float* __restrict__ x, const float* __restrict__ geo_c,
    const ushort* __restrict__ hh2b, const ushort* __restrict__ pack,
    const float* __restrict__ bc2f, const float* __restrict__ Wc3f,
    float* __restrict__ aggx, int E) {
    __shared__ ushort ar_s[32][RS];
    __shared__ ushort ac_s[32][RS];
    __shared__ float dist_s[32], attr_s[32], geo_s[32], tr_s[32];
    __shared__ float cdx_s[32], cdy_s[32], cdz_s[32];
    __shared__ int node_s[32], col_s[32];
    __shared__ float mp_s[4][32];

    const int t = threadIdx.x, lane = t & 63, w = t >> 6;
    const int quad = lane >> 4, l16 = lane & 15;
    const int base = blockIdx.x * 32;

    if (t < 32) {
        const int i = base + t;
        int r = 0, c = 0;
        float dist = 1.f, geo = 0.f, at = 0.f, emv = 0.f, cdx = 0.f, cdy = 0.f, cdz = 0.f;
        if (i < E) {
            r = ri[i]; c = ci[i];
            const float2 da = de[i];
            dist = da.x; at = da.y;
            emv = em[i];
            geo = geo_c[i];
            const float inv = 1.0f / (dist + 1.0f);
            cdx = (x[r * 3 + 0] - x[c * 3 + 0]) * inv;
            cdy = (x[r * 3 + 1] - x[c * 3 + 1]) * inv;
            cdz = (x[r * 3 + 2] - x[c * 3 + 2]) * inv;
        }
        node_s[t] = r; col_s[t] = c;
        dist_s[t] = dist; geo_s[t] = geo; attr_s[t] = at; tr_s[t] = emv;  // tr_s holds em for now
        cdx_s[t] = cdx; cdy_s[t] = cdy; cdz_s[t] = cdz;
    }
    float bc2[2], wc3[2];
#pragma unroll
    for (int nt = 0; nt < 2; ++nt) {
        const int col = w * 32 + nt * 16 + l16;
        bc2[nt] = bc2f[col]; wc3[nt] = Wc3f[col];
    }
    __syncthreads();

    {
        const int g = t >> 4;
#pragma unroll
        for (int it = 0; it < 2; ++it) {
            const int e = g * 2 + it;
            *(uint4*)&ar_s[e][l16 * 8] = *(const uint4*)(hh2b + (size_t)node_s[e] * D + l16 * 8);
            *(uint4*)&ac_s[e][l16 * 8] = *(const uint4*)(hh2b + (size_t)col_s[e] * D + l16 * 8);
        }
    }
    __syncthreads();

    short8 aext[2];
#pragma unroll
    for (int mt = 0; mt < 2; ++mt) {
        short8 v = (short8)0;
        if (quad == 0) {
            const int m = mt * 16 + l16;
            v[0] = (short)f2bs(dist_s[m]); v[1] = (short)f2bs(attr_s[m]);
            v[2] = (short)f2bs(geo_s[m]);  v[3] = (short)0x3F80;
        }
        aext[mt] = v;
    }

    // GEMM1: c1 = silu([h2r|h2c]@Wc1 + ext)
    {
        f32x4 acc[2][2] = {};
        const short8* pB = (const short8*)(pack + (size_t)PWC1 * 4096);
#pragma unroll
        for (int ks = 0; ks < 9; ++ks) {
            const short8 b0 = pB[(ks * 8 + w * 2 + 0) * 64 + lane];
            const short8 b1 = pB[(ks * 8 + w * 2 + 1) * 64 + lane];
#pragma unroll
            for (int mt = 0; mt < 2; ++mt) {
                const short8 a = (ks < 4) ? *(const short8*)&ar_s[mt * 16 + l16][ks * 32 + quad * 8]
                               : (ks < 8) ? *(const short8*)&ac_s[mt * 16 + l16][(ks - 4) * 32 + quad * 8]
                                          : aext[mt];
                acc[mt][0] = MFMA16(a, b0, acc[mt][0]);
                acc[mt][1] = MFMA16(a, b1, acc[mt][1]);
            }
        }
        __syncthreads();
#pragma unroll
        for (int mt = 0; mt < 2; ++mt)
#pragma unroll
            for (int reg = 0; reg < 4; ++reg) {
                const int row = mt * 16 + quad * 4 + reg;
#pragma unroll
                for (int nt = 0; nt < 2; ++nt)
                    ar_s[row][w * 32 + nt * 16 + l16] = f2bs(siluf(acc[mt][nt][reg]));
            }
    }
    __syncthreads();

    // GEMM2: c2 = silu(c1@Wc2 + bc2); m-partials over this wave's cols
    {
        f32x4 acc[2][2] = {};
        const short8* pB = (const short8*)(pack + (size_t)PWC2 * 4096);
#pragma unroll
        for (int ks = 0; ks < 4; ++ks) {
            const short8 b0 = pB[(ks * 8 + w * 2 + 0) * 64 + lane];
            const short8 b1 = pB[(ks * 8 + w * 2 + 1) * 64 + lane];
#pragma unroll
            for (int mt = 0; mt < 2; ++mt) {
                const short8 a = *(const short8*)&ar_s[mt * 16 + l16][ks * 32 + quad * 8];
                acc[mt][0] = MFMA16(a, b0, acc[mt][0]);
                acc[mt][1] = MFMA16(a, b1, acc[mt][1]);
            }
        }
#pragma unroll
        for (int mt = 0; mt < 2; ++mt)
#pragma unroll
            for (int reg = 0; reg < 4; ++reg) {
                float p = siluf(acc[mt][0][reg] + bc2[0]) * wc3[0]
                        + siluf(acc[mt][1][reg] + bc2[1]) * wc3[1];
                p += __shfl_xor(p, 1); p += __shfl_xor(p, 2); p += __shfl_xor(p, 4); p += __shfl_xor(p, 8);
                if (l16 == 0) mp_s[w][mt * 16 + quad * 4 + reg] = p;
            }
    }
    __syncthreads();

    if (t < 32) {
        const float m = mp_s[0][t] + mp_s[1][t] + mp_s[2][t] + mp_s[3][t];
        tr_s[t] = m * tr_s[t];   // m * em  (em stashed in tr_s)
        if (base + t >= E) tr_s[t] = 0.f;
    }
    __syncthreads();

    // segmented per-block reduce of trans into aggx (3 lanes: x,y,z)
    if (t < 3) {
        const float* cds = (t == 0) ? cdx_s : (t == 1) ? cdy_s : cdz_s;
        float acc = 0.f;
        int rprev = node_s[0];
#pragma unroll
        for (int k = 0; k < 32; ++k) {
            const int rn = node_s[k];
            if (rn != rprev) {
                atomicAdd(&aggx[rprev * 4 + t], acc);
                acc = 0.f; rprev = rn;
            }
            acc += cds[k] * tr_s[k];
        }
        atomicAdd(&aggx[rprev * 4 + t], acc);
    }
}

// ---------------- coord epilogue ----------------
__global__ void k_coord(const float* __restrict__ x, const float* __restrict__ nmask,
                        const float* __restrict__ aggx, float* __restrict__ out_x, int N) {
    const int idx = blockIdx.x * blockDim.x + threadIdx.x;
    if (idx >= N * 3) return;
    const int i = idx / 3, d = idx - i * 3;
    out_x[idx] = (x[idx] + aggx[i * 4 + d] * (1.0f / 100.0f)) * nmask[i];
}

extern "C" void kernel_launch(void* const* d_in, const int* in_sizes, int n_in,
                              void* d_out, int out_size, void* d_ws, size_t ws_size,
                              hipStream_t stream) {
    const float* h     = (const float*)d_in[0];
    const float* x     = (const float*)d_in[1];
    const int*   eidx  = (const int*)d_in[2];
    const float* nmask = (const float*)d_in[3];
    const float* emask = (const float*)d_in[4];
    const float* eattr = (const float*)d_in[5];
    const float* W_lin = (const float*)d_in[6];
    const float* b_lin = (const float*)d_in[7];
    const float* We1   = (const float*)d_in[8];
    const float* be1   = (const float*)d_in[9];
    const float* We2   = (const float*)d_in[10];
    const float* be2   = (const float*)d_in[11];
    const float* Wn1   = (const float*)d_in[12];
    const float* bn1   = (const float*)d_in[13];
    const float* Wn2   = (const float*)d_in[14];
    const float* bn2   = (const float*)d_in[15];
    const float* Wa1   = (const float*)d_in[16];
    const float* ba1   = (const float*)d_in[17];
    const float* Wa2   = (const float*)d_in[18];
    const float* ba2   = (const float*)d_in[19];
    const float* ln_g  = (const float*)d_in[20];
    const float* ln_b  = (const float*)d_in[21];
    const float* Wc1   = (const float*)d_in[22];
    const float* bc1   = (const float*)d_in[23];
    const float* Wc2   = (const float*)d_in[24];
    const float* bc2   = (const float*)d_in[25];
    const float* Wc3   = (const float*)d_in[26];

    const int N = in_sizes[0] / D;
    const int E = in_sizes[2] / 2;

    // ws layout (256-B aligned regions), ~37 MB
    char* wp = (char*)d_ws;
    auto take = [&](size_t bytes) -> void* {
        void* p = wp; wp += (bytes + 255) & ~(size_t)255; return p;
    };
    float*  agg   = (float*)take((size_t)N * D * 4);   // zeroed
    float*  aggx  = (float*)take((size_t)N * 4 * 4);   // zeroed
    int*    cnt   = (int*)take((size_t)N * 4);         // zeroed
    int*    cur   = (int*)take((size_t)N * 4);
    int*    ri    = (int*)take((size_t)E * 4);
    int*    ci    = (int*)take((size_t)E * 4);
    float2* de    = (float2*)take((size_t)E * 8);
    float*  emr   = (float*)take((size_t)E * 4);
    float*  geo_c = (float*)take((size_t)E * 4);
    ushort* hh1b  = (ushort*)take((size_t)N * D * 2);
    ushort* hh2b  = (ushort*)take((size_t)N * D * 2);
    ushort* pack  = (ushort*)take((size_t)NPACK * 4096 * 2);

    float* out_h = (float*)d_out;          // doubles as hh fp32 storage
    float* out_x = out_h + (size_t)N * D;

    const int EB = (E + 31) / 32;
    const int NB = (N + 63) / 64;

    k_zero<<<2048, 256, 0, stream>>>(agg, (long)N * D);
    k_zero<<<64, 256, 0, stream>>>(aggx, (long)N * 4);
    k_zero<<<64, 256, 0, stream>>>((float*)cnt, (long)N);
    k_packall<<<NPACK, 256, 0, stream>>>(W_lin, b_lin, Wa1, ba1, We1, be1, We2,
                                         Wn1, bn1, Wn2, Wc1, bc1, Wc2, pack);
    k_hist<<<1024, 256, 0, stream>>>(eidx, cnt, E);
    k_scan<<<1, 256, 0, stream>>>(cnt, cur, N);
    k_scatter_build<<<1024, 256, 0, stream>>>(eidx, x, eattr, emask, cur,
                                              ri, ci, de, emr, E);
    k_node_lin<<<NB, 256, 0, stream>>>(h, pack, out_h, hh1b, N);
    k_edge1<<<EB, 256, 0, stream>>>(ri, ci, de, emr, hh1b, pack,
                                    Wa2, ba2, be2, agg, geo_c, E);
    k_node2<<<NB, 256, 0, stream>>>(agg, out_h, pack, bn2, ln_g, ln_b, hh2b, N);
    k_edge2<<<EB, 256, 0, stream>>>(ri, ci, de, emr, x, geo_c, hh2b, pack,
                                    bc2, Wc3, aggx, E);
    k_coord<<<(N * 3 + 255) / 256, 256, 0, stream>>>(x, nmask, aggx, out_x, N);
}

// Round 8
// 579.885 us; speedup vs baseline: 1.2987x; 1.0731x over previous
//
#include <hip/hip_runtime.h>
#include <hip/hip_bf16.h>

// EquivariantBlock — Round 8.
// R7: edge1 VALU-bound (67% VALU, 18% MFMA, FETCH 40MB ok); remaining fat is CSR
// plumbing: scatter_build wrote 4 scattered streams (4 line-RMWs/edge), scan was
// a single 256-thread block, edge2 still gathered x[r],x[c].
// R8: one 32B AoS edge record {r,c,dist,attr,em,cd.xyz} (1 line-RMW/edge; edge
// kernels read it sequentially; x never touched after scatter_build); 1024-thread
// scan; edge1 msg overlay in fp32 (no bf16 round-trip in segmented reduce);
// single k_zero over agg|aggx|cnt.

#define D 128
#define RS 136          // LDS row stride in bf16 units (128 + 8 pad)

typedef unsigned short ushort;
typedef __attribute__((ext_vector_type(8))) short short8;
typedef __attribute__((ext_vector_type(4))) float f32x4;

__device__ __forceinline__ float siluf(float x) { return x / (1.0f + __expf(-x)); }
__device__ __forceinline__ float sigmf(float x) { return 1.0f / (1.0f + __expf(-x)); }
__device__ __forceinline__ ushort f2bs(float f) {
    __hip_bfloat16 b = __float2bfloat16(f);
    ushort u; __builtin_memcpy(&u, &b, 2); return u;
}
__device__ __forceinline__ unsigned pkbf(float lo, float hi) {
    __hip_bfloat162 h2 = __float22bfloat162_rn(make_float2(lo, hi));
    unsigned u; __builtin_memcpy(&u, &h2, 4); return u;
}
#define MFMA16(a, b, c) __builtin_amdgcn_mfma_f32_16x16x32_bf16((a), (b), (c), 0, 0, 0)

// packed-weight block offsets (units of 4096 ushorts)
#define PWLIN 0
#define PWA1  5
#define PWE1  14
#define PWE2  19
#define PWN1  23
#define PWN2  28
#define PWC1  32
#define PWC2  41
#define NPACK 45

// ---------------- zero scratch ----------------
__global__ void k_zero(float* __restrict__ p, long n) {
    long i = (long)blockIdx.x * blockDim.x + threadIdx.x;
    long stride = (long)gridDim.x * blockDim.x;
    for (; i < n; i += stride) p[i] = 0.0f;
}

// ---------------- CSR build ----------------
__global__ void k_hist(const int* __restrict__ eidx, int* __restrict__ cnt, int E) {
    int i = blockIdx.x * blockDim.x + threadIdx.x;
    const int stride = gridDim.x * blockDim.x;
    for (; i < E; i += stride) atomicAdd(&cnt[eidx[i]], 1);
}

__global__ __launch_bounds__(1024) void k_scan(const int* __restrict__ cnt,
                                               int* __restrict__ cur, int N) {
    __shared__ int part[1024];
    const int t = threadIdx.x;
    const int chunk = (N + 1023) / 1024;
    int s = 0;
    for (int k = 0; k < chunk; ++k) {
        const int i = t * chunk + k;
        if (i < N) s += cnt[i];
    }
    part[t] = s;
    __syncthreads();
    for (int d = 1; d < 1024; d <<= 1) {
        const int v = (t >= d) ? part[t - d] : 0;
        __syncthreads();
        part[t] += v;
        __syncthreads();
    }
    int base = (t == 0) ? 0 : part[t - 1];
    for (int k = 0; k < chunk; ++k) {
        const int i = t * chunk + k;
        if (i < N) { cur[i] = base; base += cnt[i]; }
    }
}

// scatter + build CSR-ordered 32B AoS records: {r,c,dist,attr | em,cdx,cdy,cdz}
__global__ void k_scatter_build(
    const int* __restrict__ eidx, const float* __restrict__ x,
    const float* __restrict__ eattr, const float* __restrict__ emask,
    int* __restrict__ cur, float4* __restrict__ rec, int E) {
    int i = blockIdx.x * blockDim.x + threadIdx.x;
    const int stride = gridDim.x * blockDim.x;
    for (; i < E; i += stride) {
        const int r = eidx[i], c = eidx[E + i];
        const int p = atomicAdd(&cur[r], 1);
        const float dx = x[r * 3 + 0] - x[c * 3 + 0];
        const float dy = x[r * 3 + 1] - x[c * 3 + 1];
        const float dz = x[r * 3 + 2] - x[c * 3 + 2];
        const float dist = sqrtf(dx * dx + dy * dy + dz * dz + 1e-8f);
        const float inv = 1.0f / (dist + 1.0f);
        rec[2 * p + 0] = make_float4(__int_as_float(r), __int_as_float(c), dist, eattr[i]);
        rec[2 * p + 1] = make_float4(emask[i], dx * inv, dy * inv, dz * inv);
    }
}

// ---------------- fused weight pack ----------------
__global__ __launch_bounds__(256) void k_packall(
    const float* __restrict__ W_lin, const float* __restrict__ b_lin,
    const float* __restrict__ Wa1, const float* __restrict__ ba1,
    const float* __restrict__ We1, const float* __restrict__ be1,
    const float* __restrict__ We2,
    const float* __restrict__ Wn1, const float* __restrict__ bn1,
    const float* __restrict__ Wn2,
    const float* __restrict__ Wc1, const float* __restrict__ bc1,
    const float* __restrict__ Wc2,
    ushort* __restrict__ pack) {
    const int b = blockIdx.x, t = threadIdx.x;
    const float* W = nullptr; const float* bias = nullptr;
    int kbase = 0, fold = 0, ext = 0, nW = 0;
    if (b < 5)       { W = W_lin; bias = b_lin; if (b == 4) { ext = 1; nW = 0; } else kbase = b * 32; }
    else if (b < 14) { int k = b - 5;  W = Wa1; bias = ba1; if (k == 8) { ext = 1; nW = 3; kbase = 256; } else { kbase = k * 32; fold = (k < 4); } }
    else if (b < 19) { int k = b - 14; W = We1; bias = be1; if (k == 4) { ext = 1; nW = 3; kbase = 128; } else kbase = k * 32; }
    else if (b < 23) { W = We2; kbase = (b - 19) * 32; }
    else if (b < 28) { int k = b - 23; W = Wn1; bias = bn1; if (k == 4) { ext = 1; nW = 0; } else kbase = k * 32; }
    else if (b < 32) { W = Wn2; kbase = (b - 28) * 32; }
    else if (b < 41) { int k = b - 32; W = Wc1; bias = bc1; if (k == 8) { ext = 1; nW = 3; kbase = 256; } else kbase = k * 32; }
    else             { W = Wc2; kbase = (b - 41) * 32; }
    ushort* dst = pack + (size_t)b * 4096;
#pragma unroll
    for (int i = 0; i < 16; ++i) {
        const int e = t + 256 * i;
        const int j = e & 7, lane = (e >> 3) & 63, nt = e >> 9;
        const int kl = (lane >> 4) * 8 + j;
        const int n = nt * 16 + (lane & 15);
        float v;
        if (!ext) {
            v = W[(kbase + kl) * D + n];
            if (fold) v += W[(kbase + kl + 128) * D + n];
        } else {
            v = (kl < nW) ? W[(kbase + kl) * D + n] : (kl == nW ? bias[n] : 0.0f);
        }
        dst[e] = f2bs(v);
    }
}

// ---------------- node_lin: hh = h @ W_lin + b (MFMA, 64 nodes/block) ----------------
__global__ __launch_bounds__(256) void k_node_lin(
    const float* __restrict__ h, const ushort* __restrict__ pack,
    float* __restrict__ hh, ushort* __restrict__ hh1b, int N) {
    __shared__ ushort hs[64][RS];
    const int t = threadIdx.x, lane = t & 63, wave = t >> 6;
    const int quad = lane >> 4, l16 = lane & 15;
    const int mh = wave >> 1, nh = wave & 1;
    const int base = blockIdx.x * 64;

#pragma unroll
    for (int q = 0; q < 8; ++q) {
        const int f = t + 256 * q;
        const int row = f >> 5, c4 = (f & 31) << 2;
        const int node = base + row;
        float4 v = make_float4(0.f, 0.f, 0.f, 0.f);
        if (node < N) v = *(const float4*)(h + (size_t)node * D + c4);
        *(uint2*)&hs[row][c4] = make_uint2(pkbf(v.x, v.y), pkbf(v.z, v.w));
    }
    __syncthreads();

    short8 aext = (short8)0;
    if (quad == 0) aext[0] = (short)0x3F80;

    f32x4 acc[2][4] = {};
    const short8* pB = (const short8*)(pack + (size_t)PWLIN * 4096);
#pragma unroll
    for (int ks = 0; ks < 5; ++ks) {
        short8 bfr[4];
#pragma unroll
        for (int nt = 0; nt < 4; ++nt) bfr[nt] = pB[(ks * 8 + nh * 4 + nt) * 64 + lane];
#pragma unroll
        for (int mt = 0; mt < 2; ++mt) {
            const short8 a = (ks < 4) ? *(const short8*)&hs[mh * 32 + mt * 16 + l16][ks * 32 + quad * 8]
                                      : aext;
#pragma unroll
            for (int nt = 0; nt < 4; ++nt) acc[mt][nt] = MFMA16(a, bfr[nt], acc[mt][nt]);
        }
    }
#pragma unroll
    for (int mt = 0; mt < 2; ++mt)
#pragma unroll
        for (int reg = 0; reg < 4; ++reg) {
            const int g = base + mh * 32 + mt * 16 + quad * 4 + reg;
            if (g < N) {
#pragma unroll
                for (int nt = 0; nt < 4; ++nt) {
                    const int col = nh * 64 + nt * 16 + l16;
                    const float v = acc[mt][nt][reg];
                    hh[(size_t)g * D + col] = v;
                    hh1b[(size_t)g * D + col] = f2bs(v);
                }
            }
        }
}

// ---------------- edge phase 1 (record stream): fused a1/m1 K-loop ----------------
__global__ __launch_bounds__(256) void k_edge1(
    const float4* __restrict__ rec,
    const ushort* __restrict__ hh1b, const ushort* __restrict__ pack,
    const float* __restrict__ Wa2f, const float* __restrict__ ba2f,
    const float* __restrict__ be2f,
    float* __restrict__ agg, float* __restrict__ geo_c, int E) {
    __shared__ ushort ab_s[2][32][RS];   // [0]=hr (m1 overlay), [1]=d ; fp32 msg overlay spans both
    __shared__ float dist_s[32], attr_s[32], geo_s[32], att_s[32], em_s[32];
    __shared__ int node_s[32], col_s[32];
    __shared__ float attp_s[4][32];

    float (*msg_s)[130] = (float(*)[130])&ab_s[0][0][0];   // 32*130*4 = 16640 <= 17408

    const int t = threadIdx.x, lane = t & 63, w = t >> 6;
    const int quad = lane >> 4, l16 = lane & 15;
    const int base = blockIdx.x * 32;

    if (t < 32) {
        const int i = base + t;
        int r = 0, c = 0; float dist = 0.f, at = 0.f, emv = 0.f;
        if (i < E) {
            const float4 ra = rec[2 * i + 0];
            const float4 rb = rec[2 * i + 1];
            r = __float_as_int(ra.x); c = __float_as_int(ra.y);
            dist = ra.z; at = ra.w; emv = rb.x;
        }
        node_s[t] = r; col_s[t] = c;
        dist_s[t] = dist; attr_s[t] = at; em_s[t] = emv;
    }
    float wa2[2], b3[2];
#pragma unroll
    for (int nt = 0; nt < 2; ++nt) {
        const int col = w * 32 + nt * 16 + l16;
        wa2[nt] = Wa2f[col]; b3[nt] = be2f[col];
    }
    __syncthreads();

    // gather hr, build d = hc - hr, geo
    {
        const int g = t >> 4;
#pragma unroll
        for (int it = 0; it < 2; ++it) {
            const int e = g * 2 + it;
            const uint4 vr = *(const uint4*)(hh1b + (size_t)node_s[e] * D + l16 * 8);
            const uint4 vc = *(const uint4*)(hh1b + (size_t)col_s[e] * D + l16 * 8);
            *(uint4*)&ab_s[0][e][l16 * 8] = vr;
            const unsigned* pr = (const unsigned*)&vr;
            const unsigned* pc = (const unsigned*)&vc;
            float s = 0.f; unsigned dw[4];
#pragma unroll
            for (int q = 0; q < 4; ++q) {
                const float r0 = __uint_as_float(pr[q] << 16), r1 = __uint_as_float(pr[q] & 0xffff0000u);
                const float c0 = __uint_as_float(pc[q] << 16), c1 = __uint_as_float(pc[q] & 0xffff0000u);
                const float d0 = c0 - r0, d1 = c1 - r1;
                s += d0 * d0 + d1 * d1;
                dw[q] = pkbf(d0, d1);
            }
            *(uint4*)&ab_s[1][e][l16 * 8] = make_uint4(dw[0], dw[1], dw[2], dw[3]);
            s += __shfl_xor(s, 1); s += __shfl_xor(s, 2); s += __shfl_xor(s, 4); s += __shfl_xor(s, 8);
            if (l16 == 0) {
                const float gg = sqrtf(s + 1e-8f);
                geo_s[e] = gg;
                if (base + e < E) geo_c[base + e] = gg;
            }
        }
    }
    __syncthreads();

    short8 aext[2];
#pragma unroll
    for (int mt = 0; mt < 2; ++mt) {
        short8 v = (short8)0;
        if (quad == 0) {
            const int m = mt * 16 + l16;
            v[0] = (short)f2bs(dist_s[m]); v[1] = (short)f2bs(attr_s[m]);
            v[2] = (short)f2bs(geo_s[m]);  v[3] = (short)0x3F80;
        }
        aext[mt] = v;
    }

    // Fused K-loop: a1 = [hr(0-3)|d(4-7)|ext(8)] @ pWa1 ; m1 = [d|ext] @ pWe1
    f32x4 accA[2][2] = {}, accM[2][2] = {};
    {
        const short8* pA = (const short8*)(pack + (size_t)PWA1 * 4096);
        const short8* pM = (const short8*)(pack + (size_t)PWE1 * 4096);
#pragma unroll
        for (int ks = 0; ks < 9; ++ks) {
            const short8 bA0 = pA[(ks * 8 + w * 2 + 0) * 64 + lane];
            const short8 bA1 = pA[(ks * 8 + w * 2 + 1) * 64 + lane];
            short8 bM0 = (short8)0, bM1 = (short8)0;
            if (ks >= 4) {
                bM0 = pM[((ks - 4) * 8 + w * 2 + 0) * 64 + lane];
                bM1 = pM[((ks - 4) * 8 + w * 2 + 1) * 64 + lane];
            }
#pragma unroll
            for (int mt = 0; mt < 2; ++mt) {
                const short8 a = (ks < 4) ? *(const short8*)&ab_s[0][mt * 16 + l16][ks * 32 + quad * 8]
                               : (ks < 8) ? *(const short8*)&ab_s[1][mt * 16 + l16][(ks - 4) * 32 + quad * 8]
                                          : aext[mt];
                accA[mt][0] = MFMA16(a, bA0, accA[mt][0]);
                accA[mt][1] = MFMA16(a, bA1, accA[mt][1]);
                if (ks >= 4) {
                    accM[mt][0] = MFMA16(a, bM0, accM[mt][0]);
                    accM[mt][1] = MFMA16(a, bM1, accM[mt][1]);
                }
            }
        }
    }
    // att partials from accA
#pragma unroll
    for (int mt = 0; mt < 2; ++mt)
#pragma unroll
        for (int reg = 0; reg < 4; ++reg) {
            float p = siluf(accA[mt][0][reg]) * wa2[0] + siluf(accA[mt][1][reg]) * wa2[1];
            p += __shfl_xor(p, 1); p += __shfl_xor(p, 2); p += __shfl_xor(p, 4); p += __shfl_xor(p, 8);
            if (l16 == 0) attp_s[w][mt * 16 + quad * 4 + reg] = p;
        }
    __syncthreads();   // attp ready; all K-loop LDS reads done

    if (t < 32)
        att_s[t] = sigmf(attp_s[0][t] + attp_s[1][t] + attp_s[2][t] + attp_s[3][t] + ba2f[0]) * em_s[t];
    // m1 overlay into ab_s[0]
#pragma unroll
    for (int mt = 0; mt < 2; ++mt)
#pragma unroll
        for (int reg = 0; reg < 4; ++reg) {
            const int row = mt * 16 + quad * 4 + reg;
#pragma unroll
            for (int nt = 0; nt < 2; ++nt)
                ab_s[0][row][w * 32 + nt * 16 + l16] = f2bs(siluf(accM[mt][nt][reg]));
        }
    __syncthreads();   // m1 + att ready

    // GEMM3: msg = (m1@We2 + be2) * att
    f32x4 acc3[2][2] = {};
    {
        const short8* pB = (const short8*)(pack + (size_t)PWE2 * 4096);
#pragma unroll
        for (int ks = 0; ks < 4; ++ks) {
            const short8 b0 = pB[(ks * 8 + w * 2 + 0) * 64 + lane];
            const short8 b1 = pB[(ks * 8 + w * 2 + 1) * 64 + lane];
#pragma unroll
            for (int mt = 0; mt < 2; ++mt) {
                const short8 a = *(const short8*)&ab_s[0][mt * 16 + l16][ks * 32 + quad * 8];
                acc3[mt][0] = MFMA16(a, b0, acc3[mt][0]);
                acc3[mt][1] = MFMA16(a, b1, acc3[mt][1]);
            }
        }
    }
    __syncthreads();   // all GEMM3 reads of ab_s done -> fp32 msg overlay spans both halves
#pragma unroll
    for (int mt = 0; mt < 2; ++mt)
#pragma unroll
        for (int reg = 0; reg < 4; ++reg) {
            const int row = mt * 16 + quad * 4 + reg;
            const float av = att_s[row];
#pragma unroll
            for (int nt = 0; nt < 2; ++nt)
                msg_s[row][w * 32 + nt * 16 + l16] = (acc3[mt][nt][reg] + b3[nt]) * av;
        }
    __syncthreads();

    // segmented reduction over CSR-sorted node ids (fp32, no cvt)
    {
        const int j = t & 127, h = t >> 7;
        float acc = 0.f;
        int rprev = node_s[h * 16];
#pragma unroll
        for (int k = 0; k < 16; ++k) {
            const int row = h * 16 + k;
            const int rn = node_s[row];
            if (rn != rprev) {
                atomicAdd(&agg[(size_t)rprev * D + j], acc);
                acc = 0.f; rprev = rn;
            }
            acc += msg_s[row][j];
        }
        atomicAdd(&agg[(size_t)rprev * D + j], acc);
    }
}

// ---------------- node2: MLP + residual + LN + silu (MFMA, 64 nodes/block) ----------------
__global__ __launch_bounds__(256) void k_node2(
    const float* __restrict__ agg, float* hio,
    const ushort* __restrict__ pack,
    const float* __restrict__ bn2f,
    const float* __restrict__ ln_g, const float* __restrict__ ln_b,
    ushort* __restrict__ hh2b, int N) {
    __shared__ ushort ag_s[64][RS];
    __shared__ float redS[2][64], redQ[2][64];
    const int t = threadIdx.x, lane = t & 63, wave = t >> 6;
    const int quad = lane >> 4, l16 = lane & 15;
    const int mh = wave >> 1, nh = wave & 1;
    const int base = blockIdx.x * 64;

#pragma unroll
    for (int q = 0; q < 8; ++q) {
        const int f = t + 256 * q;
        const int row = f >> 5, c4 = (f & 31) << 2;
        const int node = base + row;
        float4 v = make_float4(0.f, 0.f, 0.f, 0.f);
        if (node < N) v = *(const float4*)(agg + (size_t)node * D + c4);
        *(uint2*)&ag_s[row][c4] = make_uint2(pkbf(v.x, v.y), pkbf(v.z, v.w));
    }
    float bn2[4], lg[4], lb[4];
#pragma unroll
    for (int nt = 0; nt < 4; ++nt) {
        const int col = nh * 64 + nt * 16 + l16;
        bn2[nt] = bn2f[col]; lg[nt] = ln_g[col]; lb[nt] = ln_b[col];
    }
    __syncthreads();

    short8 aext = (short8)0;
    if (quad == 0) aext[0] = (short)0x3F80;

    f32x4 acc[2][4] = {};
    {
        const short8* pB = (const short8*)(pack + (size_t)PWN1 * 4096);
#pragma unroll
        for (int ks = 0; ks < 5; ++ks) {
            short8 bfr[4];
#pragma unroll
            for (int nt = 0; nt < 4; ++nt) bfr[nt] = pB[(ks * 8 + nh * 4 + nt) * 64 + lane];
#pragma unroll
            for (int mt = 0; mt < 2; ++mt) {
                const short8 a = (ks < 4) ? *(const short8*)&ag_s[mh * 32 + mt * 16 + l16][ks * 32 + quad * 8]
                                          : aext;
#pragma unroll
                for (int nt = 0; nt < 4; ++nt) acc[mt][nt] = MFMA16(a, bfr[nt], acc[mt][nt]);
            }
        }
    }
    __syncthreads();
#pragma unroll
    for (int mt = 0; mt < 2; ++mt)
#pragma unroll
        for (int reg = 0; reg < 4; ++reg) {
            const int row = mh * 32 + mt * 16 + quad * 4 + reg;
#pragma unroll
            for (int nt = 0; nt < 4; ++nt)
                ag_s[row][nh * 64 + nt * 16 + l16] = f2bs(siluf(acc[mt][nt][reg]));
        }
    __syncthreads();

    {
        const short8* pB = (const short8*)(pack + (size_t)PWN2 * 4096);
#pragma unroll
        for (int mt = 0; mt < 2; ++mt)
#pragma unroll
            for (int nt = 0; nt < 4; ++nt) acc[mt][nt] = (f32x4)0.0f;
#pragma unroll
        for (int ks = 0; ks < 4; ++ks) {
            short8 bfr[4];
#pragma unroll
            for (int nt = 0; nt < 4; ++nt) bfr[nt] = pB[(ks * 8 + nh * 4 + nt) * 64 + lane];
#pragma unroll
            for (int mt = 0; mt < 2; ++mt) {
                const short8 a = *(const short8*)&ag_s[mh * 32 + mt * 16 + l16][ks * 32 + quad * 8];
#pragma unroll
                for (int nt = 0; nt < 4; ++nt) acc[mt][nt] = MFMA16(a, bfr[nt], acc[mt][nt]);
            }
        }
    }
#pragma unroll
    for (int mt = 0; mt < 2; ++mt)
#pragma unroll
        for (int reg = 0; reg < 4; ++reg) {
            const int row = mh * 32 + mt * 16 + quad * 4 + reg;
            const int g = base + row;
            float s = 0.f, qq = 0.f;
#pragma unroll
            for (int nt = 0; nt < 4; ++nt) {
                const int col = nh * 64 + nt * 16 + l16;
                float v = acc[mt][nt][reg] + bn2[nt];
                if (g < N) v += hio[(size_t)g * D + col];
                acc[mt][nt][reg] = v;
                s += v; qq += v * v;
            }
            s += __shfl_xor(s, 1); s += __shfl_xor(s, 2); s += __shfl_xor(s, 4); s += __shfl_xor(s, 8);
            qq += __shfl_xor(qq, 1); qq += __shfl_xor(qq, 2); qq += __shfl_xor(qq, 4); qq += __shfl_xor(qq, 8);
            if (l16 == 0) { redS[nh][row] = s; redQ[nh][row] = qq; }
        }
    __syncthreads();

#pragma unroll
    for (int mt = 0; mt < 2; ++mt)
#pragma unroll
        for (int reg = 0; reg < 4; ++reg) {
            const int row = mh * 32 + mt * 16 + quad * 4 + reg;
            const int g = base + row;
            const float mu = (redS[0][row] + redS[1][row]) * (1.0f / D);
            const float var = (redQ[0][row] + redQ[1][row]) * (1.0f / D) - mu * mu;
            const float rstd = rsqrtf(var + 1e-5f);
            if (g < N) {
#pragma unroll
                for (int nt = 0; nt < 4; ++nt) {
                    const int col = nh * 64 + nt * 16 + l16;
                    const float hn = (acc[mt][nt][reg] - mu) * rstd * lg[nt] + lb[nt];
                    const float o = siluf(hn);
                    hio[(size_t)g * D + col] = o;
                    hh2b[(size_t)g * D + col] = f2bs(o);
                }
            }
        }
}

// ---------------- edge phase 2 (record stream): coord MLP -> aggx ----------------
__global__ __launch_bounds__(256) void k_edge2(
    const float4* __restrict__ rec, const float* __restrict__ geo_c,
    const ushort* __restrict__ hh2b, const ushort* __restrict__ pack,
    const float* __restrict__ bc2f, const float* __restrict__ Wc3f,
    float* __restrict__ aggx, int E) {
    __shared__ ushort ar_s[32][RS];
    __shared__ ushort ac_s[32][RS];
    __shared__ float dist_s[32], attr_s[32], geo_s[32], tr_s[32];
    __shared__ float cdx_s[32], cdy_s[32], cdz_s[32];
    __shared__ int node_s[32], col_s[32];
    __shared__ float mp_s[4][32];

    const int t = threadIdx.x, lane = t & 63, w = t >> 6;
    const int quad = lane >> 4, l16 = lane & 15;
    const int base = blockIdx.x * 32;

    if (t < 32) {
        const int i = base + t;
        int r = 0, c = 0;
        float dist = 1.f, geo = 0.f, at = 0.f, emv = 0.f, cdx = 0.f, cdy = 0.f, cdz = 0.f;
        if (i < E) {
            const float4 ra = rec[2 * i + 0];
            const float4 rb = rec[2 * i + 1];
            r = __float_as_int(ra.x); c = __float_as_int(ra.y);
            dist = ra.z; at = ra.w;
            emv = rb.x; cdx = rb.y; cdy = rb.z; cdz = rb.w;
            geo = geo_c[i];
        }
        node_s[t] = r; col_s[t] = c;
        dist_s[t] = dist; geo_s[t] = geo; attr_s[t] = at; tr_s[t] = emv;  // tr_s holds em
        cdx_s[t] = cdx; cdy_s[t] = cdy; cdz_s[t] = cdz;
    }
    float bc2[2], wc3[2];
#pragma unroll
    for (int nt = 0; nt < 2; ++nt) {
        const int col = w * 32 + nt * 16 + l16;
        bc2[nt] = bc2f[col]; wc3[nt] = Wc3f[col];
    }
    __syncthreads();

    {
        const int g = t >> 4;
#pragma unroll
        for (int it = 0; it < 2; ++it) {
            const int e = g * 2 + it;
            *(uint4*)&ar_s[e][l16 * 8] = *(const uint4*)(hh2b + (size_t)node_s[e] * D + l16 * 8);
            *(uint4*)&ac_s[e][l16 * 8] = *(const uint4*)(hh2b + (size_t)col_s[e] * D + l16 * 8);
        }
    }
    __syncthreads();

    short8 aext[2];
#pragma unroll
    for (int mt = 0; mt < 2; ++mt) {
        short8 v = (short8)0;
        if (quad == 0) {
            const int m = mt * 16 + l16;
            v[0] = (short)f2bs(dist_s[m]); v[1] = (short)f2bs(attr_s[m]);
            v[2] = (short)f2bs(geo_s[m]);  v[3] = (short)0x3F80;
        }
        aext[mt] = v;
    }

    // GEMM1: c1 = silu([h2r|h2c]@Wc1 + ext)
    {
        f32x4 acc[2][2] = {};
        const short8* pB = (const short8*)(pack + (size_t)PWC1 * 4096);
#pragma unroll
        for (int ks = 0; ks < 9; ++ks) {
            const short8 b0 = pB[(ks * 8 + w * 2 + 0) * 64 + lane];
            const short8 b1 = pB[(ks * 8 + w * 2 + 1) * 64 + lane];
#pragma unroll
            for (int mt = 0; mt < 2; ++mt) {
                const short8 a = (ks < 4) ? *(const short8*)&ar_s[mt * 16 + l16][ks * 32 + quad * 8]
                               : (ks < 8) ? *(const short8*)&ac_s[mt * 16 + l16][(ks - 4) * 32 + quad * 8]
                                          : aext[mt];
                acc[mt][0] = MFMA16(a, b0, acc[mt][0]);
                acc[mt][1] = MFMA16(a, b1, acc[mt][1]);
            }
        }
        __syncthreads();
#pragma unroll
        for (int mt = 0; mt < 2; ++mt)
#pragma unroll
            for (int reg = 0; reg < 4; ++reg) {
                const int row = mt * 16 + quad * 4 + reg;
#pragma unroll
                for (int nt = 0; nt < 2; ++nt)
                    ar_s[row][w * 32 + nt * 16 + l16] = f2bs(siluf(acc[mt][nt][reg]));
            }
    }
    __syncthreads();

    // GEMM2: c2 = silu(c1@Wc2 + bc2); m-partials over this wave's cols
    {
        f32x4 acc[2][2] = {};
        const short8* pB = (const short8*)(pack + (size_t)PWC2 * 4096);
#pragma unroll
        for (int ks = 0; ks < 4; ++ks) {
            const short8 b0 = pB[(ks * 8 + w * 2 + 0) * 64 + lane];
            const short8 b1 = pB[(ks * 8 + w * 2 + 1) * 64 + lane];
#pragma unroll
            for (int mt = 0; mt < 2; ++mt) {
                const short8 a = *(const short8*)&ar_s[mt * 16 + l16][ks * 32 + quad * 8];
                acc[mt][0] = MFMA16(a, b0, acc[mt][0]);
                acc[mt][1] = MFMA16(a, b1, acc[mt][1]);
            }
        }
#pragma unroll
        for (int mt = 0; mt < 2; ++mt)
#pragma unroll
            for (int reg = 0; reg < 4; ++reg) {
                float p = siluf(acc[mt][0][reg] + bc2[0]) * wc3[0]
                        + siluf(acc[mt][1][reg] + bc2[1]) * wc3[1];
                p += __shfl_xor(p, 1); p += __shfl_xor(p, 2); p += __shfl_xor(p, 4); p += __shfl_xor(p, 8);
                if (l16 == 0) mp_s[w][mt * 16 + quad * 4 + reg] = p;
            }
    }
    __syncthreads();

    if (t < 32) {
        const float m = mp_s[0][t] + mp_s[1][t] + mp_s[2][t] + mp_s[3][t];
        tr_s[t] = m * tr_s[t];   // m * em
        if (base + t >= E) tr_s[t] = 0.f;
    }
    __syncthreads();

    // segmented per-block reduce of trans into aggx (3 lanes: x,y,z)
    if (t < 3) {
        const float* cds = (t == 0) ? cdx_s : (t == 1) ? cdy_s : cdz_s;
        float acc = 0.f;
        int rprev = node_s[0];
#pragma unroll
        for (int k = 0; k < 32; ++k) {
            const int rn = node_s[k];
            if (rn != rprev) {
                atomicAdd(&aggx[rprev * 4 + t], acc);
                acc = 0.f; rprev = rn;
            }
            acc += cds[k] * tr_s[k];
        }
        atomicAdd(&aggx[rprev * 4 + t], acc);
    }
}

// ---------------- coord epilogue ----------------
__global__ void k_coord(const float* __restrict__ x, const float* __restrict__ nmask,
                        const float* __restrict__ aggx, float* __restrict__ out_x, int N) {
    const int idx = blockIdx.x * blockDim.x + threadIdx.x;
    if (idx >= N * 3) return;
    const int i = idx / 3, d = idx - i * 3;
    out_x[idx] = (x[idx] + aggx[i * 4 + d] * (1.0f / 100.0f)) * nmask[i];
}

extern "C" void kernel_launch(void* const* d_in, const int* in_sizes, int n_in,
                              void* d_out, int out_size, void* d_ws, size_t ws_size,
                              hipStream_t stream) {
    const float* h     = (const float*)d_in[0];
    const float* x     = (const float*)d_in[1];
    const int*   eidx  = (const int*)d_in[2];
    const float* nmask = (const float*)d_in[3];
    const float* emask = (const float*)d_in[4];
    const float* eattr = (const float*)d_in[5];
    const float* W_lin = (const float*)d_in[6];
    const float* b_lin = (const float*)d_in[7];
    const float* We1   = (const float*)d_in[8];
    const float* be1   = (const float*)d_in[9];
    const float* We2   = (const float*)d_in[10];
    const float* be2   = (const float*)d_in[11];
    const float* Wn1   = (const float*)d_in[12];
    const float* bn1   = (const float*)d_in[13];
    const float* Wn2   = (const float*)d_in[14];
    const float* bn2   = (const float*)d_in[15];
    const float* Wa1   = (const float*)d_in[16];
    const float* ba1   = (const float*)d_in[17];
    const float* Wa2   = (const float*)d_in[18];
    const float* ba2   = (const float*)d_in[19];
    const float* ln_g  = (const float*)d_in[20];
    const float* ln_b  = (const float*)d_in[21];
    const float* Wc1   = (const float*)d_in[22];
    const float* bc1   = (const float*)d_in[23];
    const float* Wc2   = (const float*)d_in[24];
    const float* bc2   = (const float*)d_in[25];
    const float* Wc3   = (const float*)d_in[26];

    const int N = in_sizes[0] / D;
    const int E = in_sizes[2] / 2;

    // ws layout (256-B aligned regions), ~34 MB
    char* wp = (char*)d_ws;
    auto take = [&](size_t bytes) -> void* {
        void* p = wp; wp += (bytes + 255) & ~(size_t)255; return p;
    };
    float*  agg   = (float*)take((size_t)N * D * 4);   // ┐ zeroed as one
    float*  aggx  = (float*)take((size_t)N * 4 * 4);   // │ contiguous
    int*    cnt   = (int*)take((size_t)N * 4);         // ┘ region
    int*    cur   = (int*)take((size_t)N * 4);
    float4* rec   = (float4*)take((size_t)E * 32);
    float*  geo_c = (float*)take((size_t)E * 4);
    ushort* hh1b  = (ushort*)take((size_t)N * D * 2);
    ushort* hh2b  = (ushort*)take((size_t)N * D * 2);
    ushort* pack  = (ushort*)take((size_t)NPACK * 4096 * 2);

    float* out_h = (float*)d_out;          // doubles as hh fp32 storage
    float* out_x = out_h + (size_t)N * D;

    const int EB = (E + 31) / 32;
    const int NB = (N + 63) / 64;
    const long zn = ((char*)(cnt + N) - (char*)agg) / 4;   // agg..cnt contiguous

    k_zero<<<2048, 256, 0, stream>>>(agg, zn);
    k_packall<<<NPACK, 256, 0, stream>>>(W_lin, b_lin, Wa1, ba1, We1, be1, We2,
                                         Wn1, bn1, Wn2, Wc1, bc1, Wc2, pack);
    k_hist<<<1024, 256, 0, stream>>>(eidx, cnt, E);
    k_scan<<<1, 1024, 0, stream>>>(cnt, cur, N);
    k_scatter_build<<<1024, 256, 0, stream>>>(eidx, x, eattr, emask, cur, rec, E);
    k_node_lin<<<NB, 256, 0, stream>>>(h, pack, out_h, hh1b, N);
    k_edge1<<<EB, 256, 0, stream>>>(rec, hh1b, pack, Wa2, ba2, be2, agg, geo_c, E);
    k_node2<<<NB, 256, 0, stream>>>(agg, out_h, pack, bn2, ln_g, ln_b, hh2b, N);
    k_edge2<<<EB, 256, 0, stream>>>(rec, geo_c, hh2b, pack, bc2, Wc3, aggx, E);
    k_coord<<<(N * 3 + 255) / 256, 256, 0, stream>>>(x, nmask, aggx, out_x, N);
}

// Round 9
// 548.559 us; speedup vs baseline: 1.3729x; 1.0571x over previous
//
#include <hip/hip_runtime.h>
#include <hip/hip_bf16.h>

// EquivariantBlock — Round 9.
// R8: edge1 233us VALU-bound (65% VALU / 18% MFMA). Disasm model: siluf/sigmf use
// IEEE fp32 division (~10-15 VALU inst each, no -ffast-math in harness); edge1 runs
// 24 silus/thread, edge2 18, node2 16. R9: silu/sigmoid via __builtin_amdgcn_rcpf
// (1 inst, 1-ulp) -> ~5 inst/silu. Everything else identical to R8.

#define D 128
#define RS 136          // LDS row stride in bf16 units (128 + 8 pad)

typedef unsigned short ushort;
typedef __attribute__((ext_vector_type(8))) short short8;
typedef __attribute__((ext_vector_type(4))) float f32x4;

__device__ __forceinline__ float rcpf(float x) { return __builtin_amdgcn_rcpf(x); }
__device__ __forceinline__ float siluf(float x) { return x * rcpf(1.0f + __expf(-x)); }
__device__ __forceinline__ float sigmf(float x) { return rcpf(1.0f + __expf(-x)); }
__device__ __forceinline__ ushort f2bs(float f) {
    __hip_bfloat16 b = __float2bfloat16(f);
    ushort u; __builtin_memcpy(&u, &b, 2); return u;
}
__device__ __forceinline__ unsigned pkbf(float lo, float hi) {
    __hip_bfloat162 h2 = __float22bfloat162_rn(make_float2(lo, hi));
    unsigned u; __builtin_memcpy(&u, &h2, 4); return u;
}
#define MFMA16(a, b, c) __builtin_amdgcn_mfma_f32_16x16x32_bf16((a), (b), (c), 0, 0, 0)

// packed-weight block offsets (units of 4096 ushorts)
#define PWLIN 0
#define PWA1  5
#define PWE1  14
#define PWE2  19
#define PWN1  23
#define PWN2  28
#define PWC1  32
#define PWC2  41
#define NPACK 45

// ---------------- zero scratch ----------------
__global__ void k_zero(float* __restrict__ p, long n) {
    long i = (long)blockIdx.x * blockDim.x + threadIdx.x;
    long stride = (long)gridDim.x * blockDim.x;
    for (; i < n; i += stride) p[i] = 0.0f;
}

// ---------------- CSR build ----------------
__global__ void k_hist(const int* __restrict__ eidx, int* __restrict__ cnt, int E) {
    int i = blockIdx.x * blockDim.x + threadIdx.x;
    const int stride = gridDim.x * blockDim.x;
    for (; i < E; i += stride) atomicAdd(&cnt[eidx[i]], 1);
}

__global__ __launch_bounds__(1024) void k_scan(const int* __restrict__ cnt,
                                               int* __restrict__ cur, int N) {
    __shared__ int part[1024];
    const int t = threadIdx.x;
    const int chunk = (N + 1023) / 1024;
    int s = 0;
    for (int k = 0; k < chunk; ++k) {
        const int i = t * chunk + k;
        if (i < N) s += cnt[i];
    }
    part[t] = s;
    __syncthreads();
    for (int d = 1; d < 1024; d <<= 1) {
        const int v = (t >= d) ? part[t - d] : 0;
        __syncthreads();
        part[t] += v;
        __syncthreads();
    }
    int base = (t == 0) ? 0 : part[t - 1];
    for (int k = 0; k < chunk; ++k) {
        const int i = t * chunk + k;
        if (i < N) { cur[i] = base; base += cnt[i]; }
    }
}

// scatter + build CSR-ordered 32B AoS records: {r,c,dist,attr | em,cdx,cdy,cdz}
__global__ void k_scatter_build(
    const int* __restrict__ eidx, const float* __restrict__ x,
    const float* __restrict__ eattr, const float* __restrict__ emask,
    int* __restrict__ cur, float4* __restrict__ rec, int E) {
    int i = blockIdx.x * blockDim.x + threadIdx.x;
    const int stride = gridDim.x * blockDim.x;
    for (; i < E; i += stride) {
        const int r = eidx[i], c = eidx[E + i];
        const int p = atomicAdd(&cur[r], 1);
        const float dx = x[r * 3 + 0] - x[c * 3 + 0];
        const float dy = x[r * 3 + 1] - x[c * 3 + 1];
        const float dz = x[r * 3 + 2] - x[c * 3 + 2];
        const float dist = sqrtf(dx * dx + dy * dy + dz * dz + 1e-8f);
        const float inv = rcpf(dist + 1.0f);
        rec[2 * p + 0] = make_float4(__int_as_float(r), __int_as_float(c), dist, eattr[i]);
        rec[2 * p + 1] = make_float4(emask[i], dx * inv, dy * inv, dz * inv);
    }
}

// ---------------- fused weight pack ----------------
__global__ __launch_bounds__(256) void k_packall(
    const float* __restrict__ W_lin, const float* __restrict__ b_lin,
    const float* __restrict__ Wa1, const float* __restrict__ ba1,
    const float* __restrict__ We1, const float* __restrict__ be1,
    const float* __restrict__ We2,
    const float* __restrict__ Wn1, const float* __restrict__ bn1,
    const float* __restrict__ Wn2,
    const float* __restrict__ Wc1, const float* __restrict__ bc1,
    const float* __restrict__ Wc2,
    ushort* __restrict__ pack) {
    const int b = blockIdx.x, t = threadIdx.x;
    const float* W = nullptr; const float* bias = nullptr;
    int kbase = 0, fold = 0, ext = 0, nW = 0;
    if (b < 5)       { W = W_lin; bias = b_lin; if (b == 4) { ext = 1; nW = 0; } else kbase = b * 32; }
    else if (b < 14) { int k = b - 5;  W = Wa1; bias = ba1; if (k == 8) { ext = 1; nW = 3; kbase = 256; } else { kbase = k * 32; fold = (k < 4); } }
    else if (b < 19) { int k = b - 14; W = We1; bias = be1; if (k == 4) { ext = 1; nW = 3; kbase = 128; } else kbase = k * 32; }
    else if (b < 23) { W = We2; kbase = (b - 19) * 32; }
    else if (b < 28) { int k = b - 23; W = Wn1; bias = bn1; if (k == 4) { ext = 1; nW = 0; } else kbase = k * 32; }
    else if (b < 32) { W = Wn2; kbase = (b - 28) * 32; }
    else if (b < 41) { int k = b - 32; W = Wc1; bias = bc1; if (k == 8) { ext = 1; nW = 3; kbase = 256; } else kbase = k * 32; }
    else             { W = Wc2; kbase = (b - 41) * 32; }
    ushort* dst = pack + (size_t)b * 4096;
#pragma unroll
    for (int i = 0; i < 16; ++i) {
        const int e = t + 256 * i;
        const int j = e & 7, lane = (e >> 3) & 63, nt = e >> 9;
        const int kl = (lane >> 4) * 8 + j;
        const int n = nt * 16 + (lane & 15);
        float v;
        if (!ext) {
            v = W[(kbase + kl) * D + n];
            if (fold) v += W[(kbase + kl + 128) * D + n];
        } else {
            v = (kl < nW) ? W[(kbase + kl) * D + n] : (kl == nW ? bias[n] : 0.0f);
        }
        dst[e] = f2bs(v);
    }
}

// ---------------- node_lin: hh = h @ W_lin + b (MFMA, 64 nodes/block) ----------------
__global__ __launch_bounds__(256) void k_node_lin(
    const float* __restrict__ h, const ushort* __restrict__ pack,
    float* __restrict__ hh, ushort* __restrict__ hh1b, int N) {
    __shared__ ushort hs[64][RS];
    const int t = threadIdx.x, lane = t & 63, wave = t >> 6;
    const int quad = lane >> 4, l16 = lane & 15;
    const int mh = wave >> 1, nh = wave & 1;
    const int base = blockIdx.x * 64;

#pragma unroll
    for (int q = 0; q < 8; ++q) {
        const int f = t + 256 * q;
        const int row = f >> 5, c4 = (f & 31) << 2;
        const int node = base + row;
        float4 v = make_float4(0.f, 0.f, 0.f, 0.f);
        if (node < N) v = *(const float4*)(h + (size_t)node * D + c4);
        *(uint2*)&hs[row][c4] = make_uint2(pkbf(v.x, v.y), pkbf(v.z, v.w));
    }
    __syncthreads();

    short8 aext = (short8)0;
    if (quad == 0) aext[0] = (short)0x3F80;

    f32x4 acc[2][4] = {};
    const short8* pB = (const short8*)(pack + (size_t)PWLIN * 4096);
#pragma unroll
    for (int ks = 0; ks < 5; ++ks) {
        short8 bfr[4];
#pragma unroll
        for (int nt = 0; nt < 4; ++nt) bfr[nt] = pB[(ks * 8 + nh * 4 + nt) * 64 + lane];
#pragma unroll
        for (int mt = 0; mt < 2; ++mt) {
            const short8 a = (ks < 4) ? *(const short8*)&hs[mh * 32 + mt * 16 + l16][ks * 32 + quad * 8]
                                      : aext;
#pragma unroll
            for (int nt = 0; nt < 4; ++nt) acc[mt][nt] = MFMA16(a, bfr[nt], acc[mt][nt]);
        }
    }
#pragma unroll
    for (int mt = 0; mt < 2; ++mt)
#pragma unroll
        for (int reg = 0; reg < 4; ++reg) {
            const int g = base + mh * 32 + mt * 16 + quad * 4 + reg;
            if (g < N) {
#pragma unroll
                for (int nt = 0; nt < 4; ++nt) {
                    const int col = nh * 64 + nt * 16 + l16;
                    const float v = acc[mt][nt][reg];
                    hh[(size_t)g * D + col] = v;
                    hh1b[(size_t)g * D + col] = f2bs(v);
                }
            }
        }
}

// ---------------- edge phase 1 (record stream): fused a1/m1 K-loop ----------------
__global__ __launch_bounds__(256) void k_edge1(
    const float4* __restrict__ rec,
    const ushort* __restrict__ hh1b, const ushort* __restrict__ pack,
    const float* __restrict__ Wa2f, const float* __restrict__ ba2f,
    const float* __restrict__ be2f,
    float* __restrict__ agg, float* __restrict__ geo_c, int E) {
    __shared__ ushort ab_s[2][32][RS];   // [0]=hr (m1 overlay), [1]=d ; fp32 msg overlay spans both
    __shared__ float dist_s[32], attr_s[32], geo_s[32], att_s[32], em_s[32];
    __shared__ int node_s[32], col_s[32];
    __shared__ float attp_s[4][32];

    float (*msg_s)[130] = (float(*)[130])&ab_s[0][0][0];   // 32*130*4 = 16640 <= 17408

    const int t = threadIdx.x, lane = t & 63, w = t >> 6;
    const int quad = lane >> 4, l16 = lane & 15;
    const int base = blockIdx.x * 32;

    if (t < 32) {
        const int i = base + t;
        int r = 0, c = 0; float dist = 0.f, at = 0.f, emv = 0.f;
        if (i < E) {
            const float4 ra = rec[2 * i + 0];
            const float4 rb = rec[2 * i + 1];
            r = __float_as_int(ra.x); c = __float_as_int(ra.y);
            dist = ra.z; at = ra.w; emv = rb.x;
        }
        node_s[t] = r; col_s[t] = c;
        dist_s[t] = dist; attr_s[t] = at; em_s[t] = emv;
    }
    float wa2[2], b3[2];
#pragma unroll
    for (int nt = 0; nt < 2; ++nt) {
        const int col = w * 32 + nt * 16 + l16;
        wa2[nt] = Wa2f[col]; b3[nt] = be2f[col];
    }
    __syncthreads();

    // gather hr, build d = hc - hr, geo
    {
        const int g = t >> 4;
#pragma unroll
        for (int it = 0; it < 2; ++it) {
            const int e = g * 2 + it;
            const uint4 vr = *(const uint4*)(hh1b + (size_t)node_s[e] * D + l16 * 8);
            const uint4 vc = *(const uint4*)(hh1b + (size_t)col_s[e] * D + l16 * 8);
            *(uint4*)&ab_s[0][e][l16 * 8] = vr;
            const unsigned* pr = (const unsigned*)&vr;
            const unsigned* pc = (const unsigned*)&vc;
            float s = 0.f; unsigned dw[4];
#pragma unroll
            for (int q = 0; q < 4; ++q) {
                const float r0 = __uint_as_float(pr[q] << 16), r1 = __uint_as_float(pr[q] & 0xffff0000u);
                const float c0 = __uint_as_float(pc[q] << 16), c1 = __uint_as_float(pc[q] & 0xffff0000u);
                const float d0 = c0 - r0, d1 = c1 - r1;
                s += d0 * d0 + d1 * d1;
                dw[q] = pkbf(d0, d1);
            }
            *(uint4*)&ab_s[1][e][l16 * 8] = make_uint4(dw[0], dw[1], dw[2], dw[3]);
            s += __shfl_xor(s, 1); s += __shfl_xor(s, 2); s += __shfl_xor(s, 4); s += __shfl_xor(s, 8);
            if (l16 == 0) {
                const float gg = sqrtf(s + 1e-8f);
                geo_s[e] = gg;
                if (base + e < E) geo_c[base + e] = gg;
            }
        }
    }
    __syncthreads();

    short8 aext[2];
#pragma unroll
    for (int mt = 0; mt < 2; ++mt) {
        short8 v = (short8)0;
        if (quad == 0) {
            const int m = mt * 16 + l16;
            v[0] = (short)f2bs(dist_s[m]); v[1] = (short)f2bs(attr_s[m]);
            v[2] = (short)f2bs(geo_s[m]);  v[3] = (short)0x3F80;
        }
        aext[mt] = v;
    }

    // Fused K-loop: a1 = [hr(0-3)|d(4-7)|ext(8)] @ pWa1 ; m1 = [d|ext] @ pWe1
    f32x4 accA[2][2] = {}, accM[2][2] = {};
    {
        const short8* pA = (const short8*)(pack + (size_t)PWA1 * 4096);
        const short8* pM = (const short8*)(pack + (size_t)PWE1 * 4096);
#pragma unroll
        for (int ks = 0; ks < 9; ++ks) {
            const short8 bA0 = pA[(ks * 8 + w * 2 + 0) * 64 + lane];
            const short8 bA1 = pA[(ks * 8 + w * 2 + 1) * 64 + lane];
            short8 bM0 = (short8)0, bM1 = (short8)0;
            if (ks >= 4) {
                bM0 = pM[((ks - 4) * 8 + w * 2 + 0) * 64 + lane];
                bM1 = pM[((ks - 4) * 8 + w * 2 + 1) * 64 + lane];
            }
#pragma unroll
            for (int mt = 0; mt < 2; ++mt) {
                const short8 a = (ks < 4) ? *(const short8*)&ab_s[0][mt * 16 + l16][ks * 32 + quad * 8]
                               : (ks < 8) ? *(const short8*)&ab_s[1][mt * 16 + l16][(ks - 4) * 32 + quad * 8]
                                          : aext[mt];
                accA[mt][0] = MFMA16(a, bA0, accA[mt][0]);
                accA[mt][1] = MFMA16(a, bA1, accA[mt][1]);
                if (ks >= 4) {
                    accM[mt][0] = MFMA16(a, bM0, accM[mt][0]);
                    accM[mt][1] = MFMA16(a, bM1, accM[mt][1]);
                }
            }
        }
    }
    // att partials from accA
#pragma unroll
    for (int mt = 0; mt < 2; ++mt)
#pragma unroll
        for (int reg = 0; reg < 4; ++reg) {
            float p = siluf(accA[mt][0][reg]) * wa2[0] + siluf(accA[mt][1][reg]) * wa2[1];
            p += __shfl_xor(p, 1); p += __shfl_xor(p, 2); p += __shfl_xor(p, 4); p += __shfl_xor(p, 8);
            if (l16 == 0) attp_s[w][mt * 16 + quad * 4 + reg] = p;
        }
    __syncthreads();   // attp ready; all K-loop LDS reads done

    if (t < 32)
        att_s[t] = sigmf(attp_s[0][t] + attp_s[1][t] + attp_s[2][t] + attp_s[3][t] + ba2f[0]) * em_s[t];
    // m1 overlay into ab_s[0]
#pragma unroll
    for (int mt = 0; mt < 2; ++mt)
#pragma unroll
        for (int reg = 0; reg < 4; ++reg) {
            const int row = mt * 16 + quad * 4 + reg;
#pragma unroll
            for (int nt = 0; nt < 2; ++nt)
                ab_s[0][row][w * 32 + nt * 16 + l16] = f2bs(siluf(accM[mt][nt][reg]));
        }
    __syncthreads();   // m1 + att ready

    // GEMM3: msg = (m1@We2 + be2) * att
    f32x4 acc3[2][2] = {};
    {
        const short8* pB = (const short8*)(pack + (size_t)PWE2 * 4096);
#pragma unroll
        for (int ks = 0; ks < 4; ++ks) {
            const short8 b0 = pB[(ks * 8 + w * 2 + 0) * 64 + lane];
            const short8 b1 = pB[(ks * 8 + w * 2 + 1) * 64 + lane];
#pragma unroll
            for (int mt = 0; mt < 2; ++mt) {
                const short8 a = *(const short8*)&ab_s[0][mt * 16 + l16][ks * 32 + quad * 8];
                acc3[mt][0] = MFMA16(a, b0, acc3[mt][0]);
                acc3[mt][1] = MFMA16(a, b1, acc3[mt][1]);
            }
        }
    }
    __syncthreads();   // all GEMM3 reads of ab_s done -> fp32 msg overlay spans both halves
#pragma unroll
    for (int mt = 0; mt < 2; ++mt)
#pragma unroll
        for (int reg = 0; reg < 4; ++reg) {
            const int row = mt * 16 + quad * 4 + reg;
            const float av = att_s[row];
#pragma unroll
            for (int nt = 0; nt < 2; ++nt)
                msg_s[row][w * 32 + nt * 16 + l16] = (acc3[mt][nt][reg] + b3[nt]) * av;
        }
    __syncthreads();

    // segmented reduction over CSR-sorted node ids (fp32, no cvt)
    {
        const int j = t & 127, h = t >> 7;
        float acc = 0.f;
        int rprev = node_s[h * 16];
#pragma unroll
        for (int k = 0; k < 16; ++k) {
            const int row = h * 16 + k;
            const int rn = node_s[row];
            if (rn != rprev) {
                atomicAdd(&agg[(size_t)rprev * D + j], acc);
                acc = 0.f; rprev = rn;
            }
            acc += msg_s[row][j];
        }
        atomicAdd(&agg[(size_t)rprev * D + j], acc);
    }
}

// ---------------- node2: MLP + residual + LN + silu (MFMA, 64 nodes/block) ----------------
__global__ __launch_bounds__(256) void k_node2(
    const float* __restrict__ agg, float* hio,
    const ushort* __restrict__ pack,
    const float* __restrict__ bn2f,
    const float* __restrict__ ln_g, const float* __restrict__ ln_b,
    ushort* __restrict__ hh2b, int N) {
    __shared__ ushort ag_s[64][RS];
    __shared__ float redS[2][64], redQ[2][64];
    const int t = threadIdx.x, lane = t & 63, wave = t >> 6;
    const int quad = lane >> 4, l16 = lane & 15;
    const int mh = wave >> 1, nh = wave & 1;
    const int base = blockIdx.x * 64;

#pragma unroll
    for (int q = 0; q < 8; ++q) {
        const int f = t + 256 * q;
        const int row = f >> 5, c4 = (f & 31) << 2;
        const int node = base + row;
        float4 v = make_float4(0.f, 0.f, 0.f, 0.f);
        if (node < N) v = *(const float4*)(agg + (size_t)node * D + c4);
        *(uint2*)&ag_s[row][c4] = make_uint2(pkbf(v.x, v.y), pkbf(v.z, v.w));
    }
    float bn2[4], lg[4], lb[4];
#pragma unroll
    for (int nt = 0; nt < 4; ++nt) {
        const int col = nh * 64 + nt * 16 + l16;
        bn2[nt] = bn2f[col]; lg[nt] = ln_g[col]; lb[nt] = ln_b[col];
    }
    __syncthreads();

    short8 aext = (short8)0;
    if (quad == 0) aext[0] = (short)0x3F80;

    f32x4 acc[2][4] = {};
    {
        const short8* pB = (const short8*)(pack + (size_t)PWN1 * 4096);
#pragma unroll
        for (int ks = 0; ks < 5; ++ks) {
            short8 bfr[4];
#pragma unroll
            for (int nt = 0; nt < 4; ++nt) bfr[nt] = pB[(ks * 8 + nh * 4 + nt) * 64 + lane];
#pragma unroll
            for (int mt = 0; mt < 2; ++mt) {
                const short8 a = (ks < 4) ? *(const short8*)&ag_s[mh * 32 + mt * 16 + l16][ks * 32 + quad * 8]
                                          : aext;
#pragma unroll
                for (int nt = 0; nt < 4; ++nt) acc[mt][nt] = MFMA16(a, bfr[nt], acc[mt][nt]);
            }
        }
    }
    __syncthreads();
#pragma unroll
    for (int mt = 0; mt < 2; ++mt)
#pragma unroll
        for (int reg = 0; reg < 4; ++reg) {
            const int row = mh * 32 + mt * 16 + quad * 4 + reg;
#pragma unroll
            for (int nt = 0; nt < 4; ++nt)
                ag_s[row][nh * 64 + nt * 16 + l16] = f2bs(siluf(acc[mt][nt][reg]));
        }
    __syncthreads();

    {
        const short8* pB = (const short8*)(pack + (size_t)PWN2 * 4096);
#pragma unroll
        for (int mt = 0; mt < 2; ++mt)
#pragma unroll
            for (int nt = 0; nt < 4; ++nt) acc[mt][nt] = (f32x4)0.0f;
#pragma unroll
        for (int ks = 0; ks < 4; ++ks) {
            short8 bfr[4];
#pragma unroll
            for (int nt = 0; nt < 4; ++nt) bfr[nt] = pB[(ks * 8 + nh * 4 + nt) * 64 + lane];
#pragma unroll
            for (int mt = 0; mt < 2; ++mt) {
                const short8 a = *(const short8*)&ag_s[mh * 32 + mt * 16 + l16][ks * 32 + quad * 8];
#pragma unroll
                for (int nt = 0; nt < 4; ++nt) acc[mt][nt] = MFMA16(a, bfr[nt], acc[mt][nt]);
            }
        }
    }
#pragma unroll
    for (int mt = 0; mt < 2; ++mt)
#pragma unroll
        for (int reg = 0; reg < 4; ++reg) {
            const int row = mh * 32 + mt * 16 + quad * 4 + reg;
            const int g = base + row;
            float s = 0.f, qq = 0.f;
#pragma unroll
            for (int nt = 0; nt < 4; ++nt) {
                const int col = nh * 64 + nt * 16 + l16;
                float v = acc[mt][nt][reg] + bn2[nt];
                if (g < N) v += hio[(size_t)g * D + col];
                acc[mt][nt][reg] = v;
                s += v; qq += v * v;
            }
            s += __shfl_xor(s, 1); s += __shfl_xor(s, 2); s += __shfl_xor(s, 4); s += __shfl_xor(s, 8);
            qq += __shfl_xor(qq, 1); qq += __shfl_xor(qq, 2); qq += __shfl_xor(qq, 4); qq += __shfl_xor(qq, 8);
            if (l16 == 0) { redS[nh][row] = s; redQ[nh][row] = qq; }
        }
    __syncthreads();

#pragma unroll
    for (int mt = 0; mt < 2; ++mt)
#pragma unroll
        for (int reg = 0; reg < 4; ++reg) {
            const int row = mh * 32 + mt * 16 + quad * 4 + reg;
            const int g = base + row;
            const float mu = (redS[0][row] + redS[1][row]) * (1.0f / D);
            const float var = (redQ[0][row] + redQ[1][row]) * (1.0f / D) - mu * mu;
            const float rstd = rsqrtf(var + 1e-5f);
            if (g < N) {
#pragma unroll
                for (int nt = 0; nt < 4; ++nt) {
                    const int col = nh * 64 + nt * 16 + l16;
                    const float hn = (acc[mt][nt][reg] - mu) * rstd * lg[nt] + lb[nt];
                    const float o = siluf(hn);
                    hio[(size_t)g * D + col] = o;
                    hh2b[(size_t)g * D + col] = f2bs(o);
                }
            }
        }
}

// ---------------- edge phase 2 (record stream): coord MLP -> aggx ----------------
__global__ __launch_bounds__(256) void k_edge2(
    const float4* __restrict__ rec, const float* __restrict__ geo_c,
    const ushort* __restrict__ hh2b, const ushort* __restrict__ pack,
    const float* __restrict__ bc2f, const float* __restrict__ Wc3f,
    float* __restrict__ aggx, int E) {
    __shared__ ushort ar_s[32][RS];
    __shared__ ushort ac_s[32][RS];
    __shared__ float dist_s[32], attr_s[32], geo_s[32], tr_s[32];
    __shared__ float cdx_s[32], cdy_s[32], cdz_s[32];
    __shared__ int node_s[32], col_s[32];
    __shared__ float mp_s[4][32];

    const int t = threadIdx.x, lane = t & 63, w = t >> 6;
    const int quad = lane >> 4, l16 = lane & 15;
    const int base = blockIdx.x * 32;

    if (t < 32) {
        const int i = base + t;
        int r = 0, c = 0;
        float dist = 1.f, geo = 0.f, at = 0.f, emv = 0.f, cdx = 0.f, cdy = 0.f, cdz = 0.f;
        if (i < E) {
            const float4 ra = rec[2 * i + 0];
            const float4 rb = rec[2 * i + 1];
            r = __float_as_int(ra.x); c = __float_as_int(ra.y);
            dist = ra.z; at = ra.w;
            emv = rb.x; cdx = rb.y; cdy = rb.z; cdz = rb.w;
            geo = geo_c[i];
        }
        node_s[t] = r; col_s[t] = c;
        dist_s[t] = dist; geo_s[t] = geo; attr_s[t] = at; tr_s[t] = emv;  // tr_s holds em
        cdx_s[t] = cdx; cdy_s[t] = cdy; cdz_s[t] = cdz;
    }
    float bc2[2], wc3[2];
#pragma unroll
    for (int nt = 0; nt < 2; ++nt) {
        const int col = w * 32 + nt * 16 + l16;
        bc2[nt] = bc2f[col]; wc3[nt] = Wc3f[col];
    }
    __syncthreads();

    {
        const int g = t >> 4;
#pragma unroll
        for (int it = 0; it < 2; ++it) {
            const int e = g * 2 + it;
            *(uint4*)&ar_s[e][l16 * 8] = *(const uint4*)(hh2b + (size_t)node_s[e] * D + l16 * 8);
            *(uint4*)&ac_s[e][l16 * 8] = *(const uint4*)(hh2b + (size_t)col_s[e] * D + l16 * 8);
        }
    }
    __syncthreads();

    short8 aext[2];
#pragma unroll
    for (int mt = 0; mt < 2; ++mt) {
        short8 v = (short8)0;
        if (quad == 0) {
            const int m = mt * 16 + l16;
            v[0] = (short)f2bs(dist_s[m]); v[1] = (short)f2bs(attr_s[m]);
            v[2] = (short)f2bs(geo_s[m]);  v[3] = (short)0x3F80;
        }
        aext[mt] = v;
    }

    // GEMM1: c1 = silu([h2r|h2c]@Wc1 + ext)
    {
        f32x4 acc[2][2] = {};
        const short8* pB = (const short8*)(pack + (size_t)PWC1 * 4096);
#pragma unroll
        for (int ks = 0; ks < 9; ++ks) {
            const short8 b0 = pB[(ks * 8 + w * 2 + 0) * 64 + lane];
            const short8 b1 = pB[(ks * 8 + w * 2 + 1) * 64 + lane];
#pragma unroll
            for (int mt = 0; mt < 2; ++mt) {
                const short8 a = (ks < 4) ? *(const short8*)&ar_s[mt * 16 + l16][ks * 32 + quad * 8]
                               : (ks < 8) ? *(const short8*)&ac_s[mt * 16 + l16][(ks - 4) * 32 + quad * 8]
                                          : aext[mt];
                acc[mt][0] = MFMA16(a, b0, acc[mt][0]);
                acc[mt][1] = MFMA16(a, b1, acc[mt][1]);
            }
        }
        __syncthreads();
#pragma unroll
        for (int mt = 0; mt < 2; ++mt)
#pragma unroll
            for (int reg = 0; reg < 4; ++reg) {
                const int row = mt * 16 + quad * 4 + reg;
#pragma unroll
                for (int nt = 0; nt < 2; ++nt)
                    ar_s[row][w * 32 + nt * 16 + l16] = f2bs(siluf(acc[mt][nt][reg]));
            }
    }
    __syncthreads();

    // GEMM2: c2 = silu(c1@Wc2 + bc2); m-partials over this wave's cols
    {
        f32x4 acc[2][2] = {};
        const short8* pB = (const short8*)(pack + (size_t)PWC2 * 4096);
#pragma unroll
        for (int ks = 0; ks < 4; ++ks) {
            const short8 b0 = pB[(ks * 8 + w * 2 + 0) * 64 + lane];
            const short8 b1 = pB[(ks * 8 + w * 2 + 1) * 64 + lane];
#pragma unroll
            for (int mt = 0; mt < 2; ++mt) {
                const short8 a = *(const short8*)&ar_s[mt * 16 + l16][ks * 32 + quad * 8];
                acc[mt][0] = MFMA16(a, b0, acc[mt][0]);
                acc[mt][1] = MFMA16(a, b1, acc[mt][1]);
            }
        }
#pragma unroll
        for (int mt = 0; mt < 2; ++mt)
#pragma unroll
            for (int reg = 0; reg < 4; ++reg) {
                float p = siluf(acc[mt][0][reg] + bc2[0]) * wc3[0]
                        + siluf(acc[mt][1][reg] + bc2[1]) * wc3[1];
                p += __shfl_xor(p, 1); p += __shfl_xor(p, 2); p += __shfl_xor(p, 4); p += __shfl_xor(p, 8);
                if (l16 == 0) mp_s[w][mt * 16 + quad * 4 + reg] = p;
            }
    }
    __syncthreads();

    if (t < 32) {
        const float m = mp_s[0][t] + mp_s[1][t] + mp_s[2][t] + mp_s[3][t];
        tr_s[t] = m * tr_s[t];   // m * em
        if (base + t >= E) tr_s[t] = 0.f;
    }
    __syncthreads();

    // segmented per-block reduce of trans into aggx (3 lanes: x,y,z)
    if (t < 3) {
        const float* cds = (t == 0) ? cdx_s : (t == 1) ? cdy_s : cdz_s;
        float acc = 0.f;
        int rprev = node_s[0];
#pragma unroll
        for (int k = 0; k < 32; ++k) {
            const int rn = node_s[k];
            if (rn != rprev) {
                atomicAdd(&aggx[rprev * 4 + t], acc);
                acc = 0.f; rprev = rn;
            }
            acc += cds[k] * tr_s[k];
        }
        atomicAdd(&aggx[rprev * 4 + t], acc);
    }
}

// ---------------- coord epilogue ----------------
__global__ void k_coord(const float* __restrict__ x, const float* __restrict__ nmask,
                        const float* __restrict__ aggx, float* __restrict__ out_x, int N) {
    const int idx = blockIdx.x * blockDim.x + threadIdx.x;
    if (idx >= N * 3) return;
    const int i = idx / 3, d = idx - i * 3;
    out_x[idx] = (x[idx] + aggx[i * 4 + d] * (1.0f / 100.0f)) * nmask[i];
}

extern "C" void kernel_launch(void* const* d_in, const int* in_sizes, int n_in,
                              void* d_out, int out_size, void* d_ws, size_t ws_size,
                              hipStream_t stream) {
    const float* h     = (const float*)d_in[0];
    const float* x     = (const float*)d_in[1];
    const int*   eidx  = (const int*)d_in[2];
    const float* nmask = (const float*)d_in[3];
    const float* emask = (const float*)d_in[4];
    const float* eattr = (const float*)d_in[5];
    const float* W_lin = (const float*)d_in[6];
    const float* b_lin = (const float*)d_in[7];
    const float* We1   = (const float*)d_in[8];
    const float* be1   = (const float*)d_in[9];
    const float* We2   = (const float*)d_in[10];
    const float* be2   = (const float*)d_in[11];
    const float* Wn1   = (const float*)d_in[12];
    const float* bn1   = (const float*)d_in[13];
    const float* Wn2   = (const float*)d_in[14];
    const float* bn2   = (const float*)d_in[15];
    const float* Wa1   = (const float*)d_in[16];
    const float* ba1   = (const float*)d_in[17];
    const float* Wa2   = (const float*)d_in[18];
    const float* ba2   = (const float*)d_in[19];
    const float* ln_g  = (const float*)d_in[20];
    const float* ln_b  = (const float*)d_in[21];
    const float* Wc1   = (const float*)d_in[22];
    const float* bc1   = (const float*)d_in[23];
    const float* Wc2   = (const float*)d_in[24];
    const float* bc2   = (const float*)d_in[25];
    const float* Wc3   = (const float*)d_in[26];

    const int N = in_sizes[0] / D;
    const int E = in_sizes[2] / 2;

    // ws layout (256-B aligned regions), ~34 MB
    char* wp = (char*)d_ws;
    auto take = [&](size_t bytes) -> void* {
        void* p = wp; wp += (bytes + 255) & ~(size_t)255; return p;
    };
    float*  agg   = (float*)take((size_t)N * D * 4);   // ┐ zeroed as one
    float*  aggx  = (float*)take((size_t)N * 4 * 4);   // │ contiguous
    int*    cnt   = (int*)take((size_t)N * 4);         // ┘ region
    int*    cur   = (int*)take((size_t)N * 4);
    float4* rec   = (float4*)take((size_t)E * 32);
    float*  geo_c = (float*)take((size_t)E * 4);
    ushort* hh1b  = (ushort*)take((size_t)N * D * 2);
    ushort* hh2b  = (ushort*)take((size_t)N * D * 2);
    ushort* pack  = (ushort*)take((size_t)NPACK * 4096 * 2);

    float* out_h = (float*)d_out;          // doubles as hh fp32 storage
    float* out_x = out_h + (size_t)N * D;

    const int EB = (E + 31) / 32;
    const int NB = (N + 63) / 64;
    const long zn = ((char*)(cnt + N) - (char*)agg) / 4;   // agg..cnt contiguous

    k_zero<<<2048, 256, 0, stream>>>(agg, zn);
    k_packall<<<NPACK, 256, 0, stream>>>(W_lin, b_lin, Wa1, ba1, We1, be1, We2,
                                         Wn1, bn1, Wn2, Wc1, bc1, Wc2, pack);
    k_hist<<<1024, 256, 0, stream>>>(eidx, cnt, E);
    k_scan<<<1, 1024, 0, stream>>>(cnt, cur, N);
    k_scatter_build<<<1024, 256, 0, stream>>>(eidx, x, eattr, emask, cur, rec, E);
    k_node_lin<<<NB, 256, 0, stream>>>(h, pack, out_h, hh1b, N);
    k_edge1<<<EB, 256, 0, stream>>>(rec, hh1b, pack, Wa2, ba2, be2, agg, geo_c, E);
    k_node2<<<NB, 256, 0, stream>>>(agg, out_h, pack, bn2, ln_g, ln_b, hh2b, N);
    k_edge2<<<EB, 256, 0, stream>>>(rec, geo_c, hh2b, pack, bc2, Wc3, aggx, E);
    k_coord<<<(N * 3 + 255) / 256, 256, 0, stream>>>(x, nmask, aggx, out_x, N);
}